// Round 2
// baseline (1975.151 us; speedup 1.0000x reference)
//
#include <hip/hip_runtime.h>
#include <hip/hip_bf16.h>

// Problem constants
#define Bz   2
#define Lz   2048
#define CINz 20
#define DMz  128
#define DIz  256
#define DSz  16
#define DTRz 8
#define DCz  4
#define NLz  6
#define NCz  6
#define EPSz 1e-5f
#define CHUNK 128
#define NCH   16   // Lz / CHUNK

__device__ __forceinline__ float siluf(float x){ return x / (1.0f + expf(-x)); }
__device__ __forceinline__ float softplusf(float x){ return (x > 20.f) ? x : log1pf(expf(x)); }

// ---- K1: embed = rmsnorm(input_ids) @ in2m_w.T + b, silu -> hs (B,L,DM)
__global__ void k_embed(const float* __restrict__ ids, const float* __restrict__ nw,
                        const float* __restrict__ w, const float* __restrict__ b,
                        float* __restrict__ hs){
  int tok = blockIdx.x;          // B*L
  int t = threadIdx.x;           // DM=128
  __shared__ float xs[CINz];
  if (t < CINz) xs[t] = ids[tok*CINz + t];
  __syncthreads();
  float ss = 0.f;
  #pragma unroll
  for (int k=0;k<CINz;k++){ float v = xs[k]; ss += v*v; }
  float rs = rsqrtf(ss/(float)CINz + EPSz);
  float acc = b[t];
  const float* wr = w + (size_t)t*CINz;
  #pragma unroll
  for (int k=0;k<CINz;k++) acc += xs[k]*rs*nw[k]*wr[k];
  hs[tok*DMz + t] = siluf(acc);
}

// ---- K2: res += hs (or res=hs), x = rmsnorm(res)*norm_w; xz = x @ in_w.T -> xin,z
__global__ void k_inproj(const float* __restrict__ hs, float* __restrict__ res,
                         const float* __restrict__ norm_w, const float* __restrict__ in_w,
                         float* __restrict__ xin, float* __restrict__ z, int first){
  int tok = blockIdx.x;
  int t = threadIdx.x;           // 256
  __shared__ __align__(16) float xs[DMz];
  if (t < DMz){
    float r = hs[tok*DMz + t];
    if (!first) r += res[tok*DMz + t];
    res[tok*DMz + t] = r;
    xs[t] = r;
  }
  __syncthreads();
  float ss = 0.f;
  const float4* xs4 = (const float4*)xs;
  #pragma unroll
  for (int k=0;k<DMz/4;k++){ float4 v = xs4[k]; ss += v.x*v.x + v.y*v.y + v.z*v.z + v.w*v.w; }
  float rs = rsqrtf(ss/(float)DMz + EPSz);
  const float4* w0 = (const float4*)(in_w + (size_t)t*DMz);
  const float4* w1 = (const float4*)(in_w + (size_t)(t+DIz)*DMz);
  const float4* nw4 = (const float4*)norm_w;
  float a0=0.f, a1=0.f;
  #pragma unroll 4
  for (int k=0;k<DMz/4;k++){
    float4 xv = xs4[k]; float4 nv = nw4[k];
    float4 wa = w0[k]; float4 wb = w1[k];
    float nx = xv.x*rs*nv.x, ny = xv.y*rs*nv.y, nz2 = xv.z*rs*nv.z, nw2 = xv.w*rs*nv.w;
    a0 += nx*wa.x + ny*wa.y + nz2*wa.z + nw2*wa.w;
    a1 += nx*wb.x + ny*wb.y + nz2*wb.z + nw2*wb.w;
  }
  xin[tok*DIz + t] = a0;
  z[tok*DIz + t]   = a1;
}

// ---- K3: depthwise causal conv + silu -> u
__global__ void k_conv(const float* __restrict__ xin, const float* __restrict__ cw,
                       const float* __restrict__ cb, float* __restrict__ u){
  int idx = blockIdx.x*blockDim.x + threadIdx.x;   // B*L*DI
  int d = idx % DIz;
  int l = (idx / DIz) % Lz;
  float acc = cb[d];
  #pragma unroll
  for (int k=0;k<DCz;k++){
    int ls = l - (DCz-1) + k;
    if (ls >= 0) acc += xin[idx + (ls - l)*DIz] * cw[d*DCz + k];
  }
  u[idx] = siluf(acc);
}

// ---- K4: xdbl = u @ xp_w.T (40); dt = softplus(dtr @ dt_w.T + dt_b); split Bm, Cm
__global__ void k_xproj(const float* __restrict__ u, const float* __restrict__ xp_w,
                        const float* __restrict__ dt_w, const float* __restrict__ dt_b,
                        float* __restrict__ dt, float* __restrict__ Bm, float* __restrict__ Cm){
  int tok = blockIdx.x;
  int t = threadIdx.x;           // 256
  __shared__ __align__(16) float us[DIz];
  __shared__ float xd[DTRz + 2*DSz];
  us[t] = u[tok*DIz + t];
  __syncthreads();
  if (t < DTRz + 2*DSz){
    const float4* w = (const float4*)(xp_w + (size_t)t*DIz);
    const float4* u4 = (const float4*)us;
    float a = 0.f;
    #pragma unroll 4
    for (int k=0;k<DIz/4;k++){ float4 uv=u4[k], wv=w[k]; a += uv.x*wv.x + uv.y*wv.y + uv.z*wv.z + uv.w*wv.w; }
    xd[t] = a;
  }
  __syncthreads();
  float s = dt_b[t];
  #pragma unroll
  for (int k=0;k<DTRz;k++) s += xd[k]*dt_w[(size_t)t*DTRz + k];
  dt[tok*DIz + t] = softplusf(s);
  if (t < DSz) Bm[tok*DSz + t] = xd[DTRz + t];
  else if (t < 2*DSz) Cm[tok*DSz + (t - DSz)] = xd[DTRz + DSz + (t - DSz)];
}

// ---- K5: chunk-local scan with h0=0: record P=prod(a), H=chunk result
__global__ void k_scan1(const float* __restrict__ dt, const float* __restrict__ u,
                        const float* __restrict__ Bm, const float* __restrict__ A_log,
                        float* __restrict__ P, float* __restrict__ H){
  int bid = blockIdx.x;                        // B*NCH*16
  int b  = bid / (NCH*16);
  int rem = bid % (NCH*16);
  int ch = rem / 16;
  int dg = rem % 16;
  int t = threadIdx.x;                         // 256 = 16 d x 16 s
  int dl = t >> 4, s = t & 15;
  int d = dg*16 + dl;
  float A = -expf(A_log[d*DSz + s]);
  float h = 0.f, Pp = 1.f;
  int t0 = ch*CHUNK;
  for (int tt=0; tt<CHUNK; tt++){
    int tok = b*Lz + t0 + tt;
    float dtv = dt[tok*DIz + d];
    float uv  = u[tok*DIz + d];
    float bv  = Bm[tok*DSz + s];
    float a = expf(dtv * A);
    h = a*h + dtv*uv*bv;
    Pp *= a;
  }
  int idx = ((ch*Bz + b)*DIz + d)*DSz + s;
  P[idx] = Pp; H[idx] = h;
}

// ---- K6: sequential combine across 16 chunks -> hstart per chunk
__global__ void k_scan2(const float* __restrict__ P, const float* __restrict__ H,
                        float* __restrict__ hstart){
  int idx = blockIdx.x*blockDim.x + threadIdx.x;   // B*DI*DS = 8192
  float h = 0.f;
  #pragma unroll
  for (int ch=0; ch<NCH; ch++){
    int j = ch*(Bz*DIz*DSz) + idx;
    hstart[j] = h;
    h = P[j]*h + H[j];
  }
}

// ---- K7: replay chunk with correct h0, produce y, gate with silu(z) -> yg
__global__ void k_scan3(const float* __restrict__ dt, const float* __restrict__ u,
                        const float* __restrict__ Bm, const float* __restrict__ Cm,
                        const float* __restrict__ z, const float* __restrict__ A_log,
                        const float* __restrict__ Dp, const float* __restrict__ hstart,
                        float* __restrict__ yg){
  int bid = blockIdx.x;
  int b  = bid / (NCH*16);
  int rem = bid % (NCH*16);
  int ch = rem / 16;
  int dg = rem % 16;
  int t = threadIdx.x;
  int dl = t >> 4, s = t & 15;
  int d = dg*16 + dl;
  float A = -expf(A_log[d*DSz + s]);
  float Dv = Dp[d];
  float h = hstart[((ch*Bz + b)*DIz + d)*DSz + s];
  int t0 = ch*CHUNK;
  for (int tt=0; tt<CHUNK; tt++){
    int tok = b*Lz + t0 + tt;
    float dtv = dt[tok*DIz + d];
    float uv  = u[tok*DIz + d];
    float bv  = Bm[tok*DSz + s];
    float cv  = Cm[tok*DSz + s];
    float a = expf(dtv * A);
    h = a*h + dtv*uv*bv;
    float p = h*cv;
    p += __shfl_xor(p, 1, 16);
    p += __shfl_xor(p, 2, 16);
    p += __shfl_xor(p, 4, 16);
    p += __shfl_xor(p, 8, 16);
    if (s == 0){
      float y = p + uv*Dv;
      float zv = z[tok*DIz + d];
      yg[tok*DIz + d] = y * (zv / (1.f + expf(-zv)));
    }
  }
}

// ---- K8: hs = yg @ out_w.T  (256 -> 128)
__global__ void k_outproj(const float* __restrict__ yg, const float* __restrict__ out_w,
                          float* __restrict__ hs){
  int tok = blockIdx.x; int t = threadIdx.x;   // 128
  __shared__ __align__(16) float ys[DIz];
  ys[t] = yg[tok*DIz + t];
  ys[t + DMz] = yg[tok*DIz + t + DMz];
  __syncthreads();
  const float4* w = (const float4*)(out_w + (size_t)t*DIz);
  const float4* y4 = (const float4*)ys;
  float a = 0.f;
  #pragma unroll 4
  for (int k=0;k<DIz/4;k++){
    float4 yv = y4[k], wv = w[k];
    a += yv.x*wv.x + yv.y*wv.y + yv.z*wv.z + yv.w*wv.w;
  }
  hs[tok*DMz + t] = a;
}

// ---- K9: final rmsnorm(hs+res) @ head_w.T + head_b, softmax -> out (float32!)
__global__ void k_head(const float* __restrict__ hs, const float* __restrict__ res,
                       const float* __restrict__ nfw, const float* __restrict__ hw,
                       const float* __restrict__ hb, float* __restrict__ out){
  int b = blockIdx.x; int t = threadIdx.x;   // 128
  __shared__ float xs[DMz];
  __shared__ float logits[NCz];
  int tok = b*Lz + (Lz-1);
  xs[t] = hs[tok*DMz + t] + res[tok*DMz + t];
  __syncthreads();
  float ss = 0.f;
  #pragma unroll
  for (int k=0;k<DMz;k++){ float v = xs[k]; ss += v*v; }
  float rs = rsqrtf(ss/(float)DMz + EPSz);
  if (t < NCz){
    float a = hb[t];
    const float* wr = hw + (size_t)t*DMz;
    for (int k=0;k<DMz;k++) a += xs[k]*rs*nfw[k]*wr[k];
    logits[t] = a;
  }
  __syncthreads();
  if (t == 0){
    float m = logits[0];
    for (int c=1;c<NCz;c++) m = fmaxf(m, logits[c]);
    float ssum = 0.f; float e[NCz];
    for (int c=0;c<NCz;c++){ e[c] = expf(logits[c]-m); ssum += e[c]; }
    for (int c=0;c<NCz;c++) out[b*NCz + c] = e[c]/ssum;
  }
}

extern "C" void kernel_launch(void* const* d_in, const int* in_sizes, int n_in,
                              void* d_out, int out_size, void* d_ws, size_t ws_size,
                              hipStream_t stream){
  const float* input_ids  = (const float*)d_in[0];
  const float* in_norm_w  = (const float*)d_in[1];
  const float* in2m_w     = (const float*)d_in[2];
  const float* in2m_b     = (const float*)d_in[3];
  const float* norm_w     = (const float*)d_in[4];
  const float* in_proj_w  = (const float*)d_in[5];
  const float* conv_w     = (const float*)d_in[6];
  const float* conv_b     = (const float*)d_in[7];
  const float* x_proj_w   = (const float*)d_in[8];
  const float* dt_proj_w  = (const float*)d_in[9];
  const float* dt_proj_b  = (const float*)d_in[10];
  const float* A_log      = (const float*)d_in[11];
  const float* D_param    = (const float*)d_in[12];
  const float* out_proj_w = (const float*)d_in[13];
  const float* norm_f_w   = (const float*)d_in[14];
  const float* head_w     = (const float*)d_in[15];
  const float* head_b     = (const float*)d_in[16];

  float* ws  = (float*)d_ws;
  float* res = ws;                  // B*L*DM   = 524288
  float* hs  = res + 524288;        // B*L*DM
  float* xin = hs  + 524288;        // B*L*DI (reused as y_gated)
  float* zb  = xin + 1048576;       // B*L*DI
  float* ub  = zb  + 1048576;       // B*L*DI
  float* dtb = ub  + 1048576;       // B*L*DI
  float* Bmb = dtb + 1048576;       // B*L*DS
  float* Cmb = Bmb + 65536;         // B*L*DS
  float* Pb  = Cmb + 65536;         // NCH*B*DI*DS = 131072
  float* Hb  = Pb  + 131072;
  float* hst = Hb  + 131072;

  k_embed<<<Bz*Lz, DMz, 0, stream>>>(input_ids, in_norm_w, in2m_w, in2m_b, hs);
  for (int i=0;i<NLz;i++){
    k_inproj<<<Bz*Lz, 256, 0, stream>>>(hs, res, norm_w + i*DMz,
                                        in_proj_w + (size_t)i*2*DIz*DMz, xin, zb, i==0);
    k_conv<<<(Bz*Lz*DIz)/256, 256, 0, stream>>>(xin, conv_w + i*DIz*DCz, conv_b + i*DIz, ub);
    k_xproj<<<Bz*Lz, 256, 0, stream>>>(ub, x_proj_w + (size_t)i*(DTRz+2*DSz)*DIz,
                                       dt_proj_w + (size_t)i*DIz*DTRz, dt_proj_b + i*DIz,
                                       dtb, Bmb, Cmb);
    k_scan1<<<Bz*NCH*16, 256, 0, stream>>>(dtb, ub, Bmb, A_log + i*DIz*DSz, Pb, Hb);
    k_scan2<<<(Bz*DIz*DSz)/256, 256, 0, stream>>>(Pb, Hb, hst);
    k_scan3<<<Bz*NCH*16, 256, 0, stream>>>(dtb, ub, Bmb, Cmb, zb, A_log + i*DIz*DSz,
                                           D_param + i*DIz, hst, xin);
    k_outproj<<<Bz*Lz, DMz, 0, stream>>>(xin, out_proj_w + (size_t)i*DMz*DIz, hs);
  }
  k_head<<<Bz, DMz, 0, stream>>>(hs, res, norm_f_w, head_w, head_b, (float*)d_out);
}

// Round 3
// 1541.015 us; speedup vs baseline: 1.2817x; 1.2817x over previous
//
#include <hip/hip_runtime.h>
#include <hip/hip_bf16.h>

// Problem constants
#define Bz   2
#define Lz   2048
#define CINz 20
#define DMz  128
#define DIz  256
#define DSz  16
#define DTRz 8
#define DCz  4
#define NLz  6
#define NCz  6
#define EPSz 1e-5f
#define CHUNK 128
#define NCH   16   // Lz / CHUNK

__device__ __forceinline__ float siluf(float x){ return x / (1.0f + expf(-x)); }
__device__ __forceinline__ float softplusf(float x){ return (x > 20.f) ? x : log1pf(expf(x)); }

// ---- K1: embed = rmsnorm(input_ids) @ in2m_w.T + b, silu -> hs (B,L,DM)
__global__ void k_embed(const float* __restrict__ ids, const float* __restrict__ nw,
                        const float* __restrict__ w, const float* __restrict__ b,
                        float* __restrict__ hs){
  int tok = blockIdx.x;          // B*L
  int t = threadIdx.x;           // DM=128
  __shared__ float xs[CINz];
  if (t < CINz) xs[t] = ids[tok*CINz + t];
  __syncthreads();
  float ss = 0.f;
  #pragma unroll
  for (int k=0;k<CINz;k++){ float v = xs[k]; ss += v*v; }
  float rs = rsqrtf(ss/(float)CINz + EPSz);
  float acc = b[t];
  const float* wr = w + (size_t)t*CINz;
  #pragma unroll
  for (int k=0;k<CINz;k++) acc += xs[k]*rs*nw[k]*wr[k];
  hs[tok*DMz + t] = siluf(acc);
}

// ---- K2a: res update + rmsnorm*norm_w -> xn   (4 tokens per block, 1 wave each)
__global__ void k_norm(const float* __restrict__ hs, float* __restrict__ res,
                       const float* __restrict__ norm_w, float* __restrict__ xn, int first){
  int tok = blockIdx.x*4 + (threadIdx.x >> 6);
  int lane = threadIdx.x & 63;
  float2 h = *(const float2*)(hs + (size_t)tok*DMz + lane*2);
  float2 r2;
  if (first){ r2 = h; }
  else { float2 rr = *(const float2*)(res + (size_t)tok*DMz + lane*2);
         r2 = make_float2(h.x+rr.x, h.y+rr.y); }
  *(float2*)(res + (size_t)tok*DMz + lane*2) = r2;
  float ss = r2.x*r2.x + r2.y*r2.y;
  #pragma unroll
  for (int off=32; off; off>>=1) ss += __shfl_xor(ss, off);
  float rs = rsqrtf(ss*(1.0f/DMz) + EPSz);
  float2 nw = *(const float2*)(norm_w + lane*2);
  *(float2*)(xn + (size_t)tok*DMz + lane*2) = make_float2(r2.x*rs*nw.x, r2.y*rs*nw.y);
}

// ---- K2b: xz = xn @ in_w.T   M=4096 N=512 K=128, tile 64x128, micro 4x8
#define TTI 64
#define NTI 128
__global__ void k_gemm_in(const float* __restrict__ xn, const float* __restrict__ in_w,
                          float* __restrict__ xin, float* __restrict__ zb){
  __shared__ __align__(16) float As[TTI][132];
  int tb = blockIdx.x, nb = blockIdx.y, tid = threadIdx.x;
  const float4* src = (const float4*)(xn + (size_t)tb*TTI*DMz);
  #pragma unroll
  for (int i=tid; i<TTI*DMz/4; i+=256){
    int row = i >> 5, col = i & 31;
    *(float4*)&As[row][col*4] = src[i];
  }
  __syncthreads();
  int c0 = nb*NTI + (tid & 15)*8;     // global output col (8 per thread)
  int t0 = (tid >> 4)*4;              // local token (4 per thread)
  const float* wb = in_w + (size_t)c0*DMz;
  float acc[4][8] = {};
  for (int k=0;k<DMz;k+=4){
    float4 a0 = *(const float4*)&As[t0+0][k];
    float4 a1 = *(const float4*)&As[t0+1][k];
    float4 a2 = *(const float4*)&As[t0+2][k];
    float4 a3 = *(const float4*)&As[t0+3][k];
    #pragma unroll
    for (int r=0;r<8;r++){
      float4 w = *(const float4*)(wb + (size_t)r*DMz + k);
      acc[0][r] = fmaf(a0.x,w.x, fmaf(a0.y,w.y, fmaf(a0.z,w.z, fmaf(a0.w,w.w, acc[0][r]))));
      acc[1][r] = fmaf(a1.x,w.x, fmaf(a1.y,w.y, fmaf(a1.z,w.z, fmaf(a1.w,w.w, acc[1][r]))));
      acc[2][r] = fmaf(a2.x,w.x, fmaf(a2.y,w.y, fmaf(a2.z,w.z, fmaf(a2.w,w.w, acc[2][r]))));
      acc[3][r] = fmaf(a3.x,w.x, fmaf(a3.y,w.y, fmaf(a3.z,w.z, fmaf(a3.w,w.w, acc[3][r]))));
    }
  }
  int gt = tb*TTI + t0;
  #pragma unroll
  for (int j=0;j<4;j++){
    #pragma unroll
    for (int r=0;r<8;r++){
      int c = c0 + r;
      if (c < DIz) xin[(size_t)(gt+j)*DIz + c] = acc[j][r];
      else         zb [(size_t)(gt+j)*DIz + (c-DIz)] = acc[j][r];
    }
  }
}

// ---- K3: depthwise causal conv + silu -> u
__global__ void k_conv(const float* __restrict__ xin, const float* __restrict__ cw,
                       const float* __restrict__ cb, float* __restrict__ u){
  int idx = blockIdx.x*blockDim.x + threadIdx.x;   // B*L*DI
  int d = idx % DIz;
  int l = (idx / DIz) % Lz;
  float acc = cb[d];
  #pragma unroll
  for (int k=0;k<DCz;k++){
    int ls = l - (DCz-1) + k;
    if (ls >= 0) acc += xin[idx + (ls - l)*DIz] * cw[d*DCz + k];
  }
  u[idx] = siluf(acc);
}

// ---- K4: xdbl = u @ xp_w.T (40); dt = softplus(dtr @ dt_w.T + dt_b); split Bm, Cm
__global__ void k_xproj(const float* __restrict__ u, const float* __restrict__ xp_w,
                        const float* __restrict__ dt_w, const float* __restrict__ dt_b,
                        float* __restrict__ dt, float* __restrict__ Bm, float* __restrict__ Cm){
  int tok = blockIdx.x;
  int t = threadIdx.x;           // 256
  __shared__ __align__(16) float us[DIz];
  __shared__ float xd[DTRz + 2*DSz];
  us[t] = u[tok*DIz + t];
  __syncthreads();
  if (t < 160){
    int c = t >> 2;              // 0..39
    int kg = t & 3;              // K-chunk of 64
    const float4* w  = (const float4*)(xp_w + (size_t)c*DIz + kg*64);
    const float4* u4 = (const float4*)(us + kg*64);
    float a = 0.f;
    #pragma unroll
    for (int k=0;k<16;k++){ float4 uv=u4[k], wv=w[k];
      a += uv.x*wv.x + uv.y*wv.y + uv.z*wv.z + uv.w*wv.w; }
    a += __shfl_down(a, 2);
    a += __shfl_down(a, 1);
    if (kg == 0) xd[c] = a;
  }
  __syncthreads();
  float s = dt_b[t];
  #pragma unroll
  for (int k=0;k<DTRz;k++) s += xd[k]*dt_w[(size_t)t*DTRz + k];
  dt[tok*DIz + t] = softplusf(s);
  if (t < DSz) Bm[tok*DSz + t] = xd[DTRz + t];
  else if (t < 2*DSz) Cm[tok*DSz + (t - DSz)] = xd[DTRz + DSz + (t - DSz)];
}

// ---- K5: chunk-local scan with h0=0: record P=prod(a), H=chunk result
__global__ void k_scan1(const float* __restrict__ dt, const float* __restrict__ u,
                        const float* __restrict__ Bm, const float* __restrict__ A_log,
                        float* __restrict__ P, float* __restrict__ H){
  int bid = blockIdx.x;                        // B*NCH*16
  int b  = bid / (NCH*16);
  int rem = bid % (NCH*16);
  int ch = rem / 16;
  int dg = rem % 16;
  int t = threadIdx.x;                         // 256 = 16 d x 16 s
  int dl = t >> 4, s = t & 15;
  int d = dg*16 + dl;
  float A = -expf(A_log[d*DSz + s]);
  float h = 0.f, Pp = 1.f;
  int t0 = ch*CHUNK;
  for (int tt=0; tt<CHUNK; tt++){
    int tok = b*Lz + t0 + tt;
    float dtv = dt[tok*DIz + d];
    float uv  = u[tok*DIz + d];
    float bv  = Bm[tok*DSz + s];
    float a = expf(dtv * A);
    h = a*h + dtv*uv*bv;
    Pp *= a;
  }
  int idx = ((ch*Bz + b)*DIz + d)*DSz + s;
  P[idx] = Pp; H[idx] = h;
}

// ---- K6: sequential combine across 16 chunks -> hstart per chunk
__global__ void k_scan2(const float* __restrict__ P, const float* __restrict__ H,
                        float* __restrict__ hstart){
  int idx = blockIdx.x*blockDim.x + threadIdx.x;   // B*DI*DS = 8192
  float h = 0.f;
  #pragma unroll
  for (int ch=0; ch<NCH; ch++){
    int j = ch*(Bz*DIz*DSz) + idx;
    hstart[j] = h;
    h = P[j]*h + H[j];
  }
}

// ---- K7: replay chunk with correct h0, produce y, gate with silu(z) -> yg
__global__ void k_scan3(const float* __restrict__ dt, const float* __restrict__ u,
                        const float* __restrict__ Bm, const float* __restrict__ Cm,
                        const float* __restrict__ z, const float* __restrict__ A_log,
                        const float* __restrict__ Dp, const float* __restrict__ hstart,
                        float* __restrict__ yg){
  int bid = blockIdx.x;
  int b  = bid / (NCH*16);
  int rem = bid % (NCH*16);
  int ch = rem / 16;
  int dg = rem % 16;
  int t = threadIdx.x;
  int dl = t >> 4, s = t & 15;
  int d = dg*16 + dl;
  float A = -expf(A_log[d*DSz + s]);
  float Dv = Dp[d];
  float h = hstart[((ch*Bz + b)*DIz + d)*DSz + s];
  int t0 = ch*CHUNK;
  for (int tt=0; tt<CHUNK; tt++){
    int tok = b*Lz + t0 + tt;
    float dtv = dt[tok*DIz + d];
    float uv  = u[tok*DIz + d];
    float bv  = Bm[tok*DSz + s];
    float cv  = Cm[tok*DSz + s];
    float a = expf(dtv * A);
    h = a*h + dtv*uv*bv;
    float p = h*cv;
    p += __shfl_xor(p, 1, 16);
    p += __shfl_xor(p, 2, 16);
    p += __shfl_xor(p, 4, 16);
    p += __shfl_xor(p, 8, 16);
    if (s == 0){
      float y = p + uv*Dv;
      float zv = z[tok*DIz + d];
      yg[tok*DIz + d] = y * (zv / (1.f + expf(-zv)));
    }
  }
}

// ---- K8: hs = yg @ out_w.T   M=4096 N=128 K=256, tile 32x64, micro 1x8
__global__ void k_gemm_out(const float* __restrict__ yg, const float* __restrict__ out_w,
                           float* __restrict__ hs){
  __shared__ __align__(16) float As[32][260];
  int tb = blockIdx.x, nb = blockIdx.y, tid = threadIdx.x;
  const float4* src = (const float4*)(yg + (size_t)tb*32*DIz);
  #pragma unroll
  for (int i=tid; i<32*DIz/4; i+=256){
    int row = i >> 6, col = i & 63;
    *(float4*)&As[row][col*4] = src[i];
  }
  __syncthreads();
  int c0 = nb*64 + (tid & 7)*8;
  int t0 = tid >> 3;                 // 0..31
  const float* wb = out_w + (size_t)c0*DIz;
  float acc[8] = {};
  for (int k=0;k<DIz;k+=4){
    float4 a = *(const float4*)&As[t0][k];
    #pragma unroll
    for (int r=0;r<8;r++){
      float4 w = *(const float4*)(wb + (size_t)r*DIz + k);
      acc[r] = fmaf(a.x,w.x, fmaf(a.y,w.y, fmaf(a.z,w.z, fmaf(a.w,w.w, acc[r]))));
    }
  }
  int gt = tb*32 + t0;
  #pragma unroll
  for (int r=0;r<8;r++) hs[(size_t)gt*DMz + c0 + r] = acc[r];
}

// ---- K9: final rmsnorm(hs+res) @ head_w.T + head_b, softmax -> out (float32)
__global__ void k_head(const float* __restrict__ hs, const float* __restrict__ res,
                       const float* __restrict__ nfw, const float* __restrict__ hw,
                       const float* __restrict__ hb, float* __restrict__ out){
  int b = blockIdx.x; int t = threadIdx.x;   // 128
  __shared__ float xs[DMz];
  __shared__ float logits[NCz];
  int tok = b*Lz + (Lz-1);
  xs[t] = hs[tok*DMz + t] + res[tok*DMz + t];
  __syncthreads();
  float ss = 0.f;
  #pragma unroll
  for (int k=0;k<DMz;k++){ float v = xs[k]; ss += v*v; }
  float rs = rsqrtf(ss/(float)DMz + EPSz);
  if (t < NCz){
    float a = hb[t];
    const float* wr = hw + (size_t)t*DMz;
    for (int k=0;k<DMz;k++) a += xs[k]*rs*nfw[k]*wr[k];
    logits[t] = a;
  }
  __syncthreads();
  if (t == 0){
    float m = logits[0];
    for (int c=1;c<NCz;c++) m = fmaxf(m, logits[c]);
    float ssum = 0.f; float e[NCz];
    for (int c=0;c<NCz;c++){ e[c] = expf(logits[c]-m); ssum += e[c]; }
    for (int c=0;c<NCz;c++) out[b*NCz + c] = e[c]/ssum;
  }
}

extern "C" void kernel_launch(void* const* d_in, const int* in_sizes, int n_in,
                              void* d_out, int out_size, void* d_ws, size_t ws_size,
                              hipStream_t stream){
  const float* input_ids  = (const float*)d_in[0];
  const float* in_norm_w  = (const float*)d_in[1];
  const float* in2m_w     = (const float*)d_in[2];
  const float* in2m_b     = (const float*)d_in[3];
  const float* norm_w     = (const float*)d_in[4];
  const float* in_proj_w  = (const float*)d_in[5];
  const float* conv_w     = (const float*)d_in[6];
  const float* conv_b     = (const float*)d_in[7];
  const float* x_proj_w   = (const float*)d_in[8];
  const float* dt_proj_w  = (const float*)d_in[9];
  const float* dt_proj_b  = (const float*)d_in[10];
  const float* A_log      = (const float*)d_in[11];
  const float* D_param    = (const float*)d_in[12];
  const float* out_proj_w = (const float*)d_in[13];
  const float* norm_f_w   = (const float*)d_in[14];
  const float* head_w     = (const float*)d_in[15];
  const float* head_b     = (const float*)d_in[16];

  float* ws  = (float*)d_ws;
  float* res = ws;                  // B*L*DM   = 524288
  float* hs  = res + 524288;        // B*L*DM
  float* xin = hs  + 524288;        // B*L*DI (reused as y_gated)
  float* zb  = xin + 1048576;       // B*L*DI
  float* ub  = zb  + 1048576;       // B*L*DI
  float* dtb = ub  + 1048576;       // B*L*DI
  float* Bmb = dtb + 1048576;       // B*L*DS
  float* Cmb = Bmb + 65536;         // B*L*DS
  float* Pb  = Cmb + 65536;         // NCH*B*DI*DS = 131072
  float* Hb  = Pb  + 131072;
  float* hst = Hb  + 131072;
  float* xn  = dtb;                 // alias: xn dead before k_xproj writes dtb

  k_embed<<<Bz*Lz, DMz, 0, stream>>>(input_ids, in_norm_w, in2m_w, in2m_b, hs);
  for (int i=0;i<NLz;i++){
    k_norm<<<(Bz*Lz)/4, 256, 0, stream>>>(hs, res, norm_w + i*DMz, xn, i==0);
    k_gemm_in<<<dim3((Bz*Lz)/TTI, 4), 256, 0, stream>>>(xn, in_proj_w + (size_t)i*2*DIz*DMz, xin, zb);
    k_conv<<<(Bz*Lz*DIz)/256, 256, 0, stream>>>(xin, conv_w + i*DIz*DCz, conv_b + i*DIz, ub);
    k_xproj<<<Bz*Lz, 256, 0, stream>>>(ub, x_proj_w + (size_t)i*(DTRz+2*DSz)*DIz,
                                       dt_proj_w + (size_t)i*DIz*DTRz, dt_proj_b + i*DIz,
                                       dtb, Bmb, Cmb);
    k_scan1<<<Bz*NCH*16, 256, 0, stream>>>(dtb, ub, Bmb, A_log + i*DIz*DSz, Pb, Hb);
    k_scan2<<<(Bz*DIz*DSz)/256, 256, 0, stream>>>(Pb, Hb, hst);
    k_scan3<<<Bz*NCH*16, 256, 0, stream>>>(dtb, ub, Bmb, Cmb, zb, A_log + i*DIz*DSz,
                                           D_param + i*DIz, hst, xin);
    k_gemm_out<<<dim3((Bz*Lz)/32, 2), 256, 0, stream>>>(xin, out_proj_w + (size_t)i*DMz*DIz, hs);
  }
  k_head<<<Bz, DMz, 0, stream>>>(hs, res, norm_f_w, head_w, head_b, (float*)d_out);
}

// Round 4
// 1062.906 us; speedup vs baseline: 1.8583x; 1.4498x over previous
//
#include <hip/hip_runtime.h>
#include <hip/hip_bf16.h>

// Problem constants
#define Bz   2
#define Lz   2048
#define CINz 20
#define DMz  128
#define DIz  256
#define DSz  16
#define DTRz 8
#define DCz  4
#define NLz  6
#define NCz  6
#define EPSz 1e-5f
#define CHUNK 64
#define NCH   32   // Lz / CHUNK
#define UB    8    // scan unroll batch

__device__ __forceinline__ float siluf(float x){ return x / (1.0f + expf(-x)); }
__device__ __forceinline__ float softplusf(float x){ return (x > 20.f) ? x : log1pf(expf(x)); }

// ---- K1: embed = rmsnorm(input_ids) @ in2m_w.T + b, silu -> hs (B,L,DM)
__global__ void k_embed(const float* __restrict__ ids, const float* __restrict__ nw,
                        const float* __restrict__ w, const float* __restrict__ b,
                        float* __restrict__ hs){
  int tok = blockIdx.x;          // B*L
  int t = threadIdx.x;           // DM=128
  __shared__ float xs[CINz];
  if (t < CINz) xs[t] = ids[tok*CINz + t];
  __syncthreads();
  float ss = 0.f;
  #pragma unroll
  for (int k=0;k<CINz;k++){ float v = xs[k]; ss += v*v; }
  float rs = rsqrtf(ss/(float)CINz + EPSz);
  float acc = b[t];
  const float* wr = w + (size_t)t*CINz;
  #pragma unroll
  for (int k=0;k<CINz;k++) acc += xs[k]*rs*nw[k]*wr[k];
  hs[tok*DMz + t] = siluf(acc);
}

// ---- K2a: res update + rmsnorm*norm_w -> xn   (4 tokens per block, 1 wave each)
__global__ void k_norm(const float* __restrict__ hs, float* __restrict__ res,
                       const float* __restrict__ norm_w, float* __restrict__ xn, int first){
  int tok = blockIdx.x*4 + (threadIdx.x >> 6);
  int lane = threadIdx.x & 63;
  float2 h = *(const float2*)(hs + (size_t)tok*DMz + lane*2);
  float2 r2;
  if (first){ r2 = h; }
  else { float2 rr = *(const float2*)(res + (size_t)tok*DMz + lane*2);
         r2 = make_float2(h.x+rr.x, h.y+rr.y); }
  *(float2*)(res + (size_t)tok*DMz + lane*2) = r2;
  float ss = r2.x*r2.x + r2.y*r2.y;
  #pragma unroll
  for (int off=32; off; off>>=1) ss += __shfl_xor(ss, off);
  float rs = rsqrtf(ss*(1.0f/DMz) + EPSz);
  float2 nw = *(const float2*)(norm_w + lane*2);
  *(float2*)(xn + (size_t)tok*DMz + lane*2) = make_float2(r2.x*rs*nw.x, r2.y*rs*nw.y);
}

// ---- K2b: xz = xn @ in_w.T   M=4096 N=512 K=128, tile 64x128, micro 4x8
#define TTI 64
#define NTI 128
__global__ void k_gemm_in(const float* __restrict__ xn, const float* __restrict__ in_w,
                          float* __restrict__ xin, float* __restrict__ zb){
  __shared__ __align__(16) float As[TTI][132];
  int tb = blockIdx.x, nb = blockIdx.y, tid = threadIdx.x;
  const float4* src = (const float4*)(xn + (size_t)tb*TTI*DMz);
  #pragma unroll
  for (int i=tid; i<TTI*DMz/4; i+=256){
    int row = i >> 5, col = i & 31;
    *(float4*)&As[row][col*4] = src[i];
  }
  __syncthreads();
  int c0 = nb*NTI + (tid & 15)*8;     // global output col (8 per thread)
  int t0 = (tid >> 4)*4;              // local token (4 per thread)
  const float* wb = in_w + (size_t)c0*DMz;
  float acc[4][8] = {};
  for (int k=0;k<DMz;k+=4){
    float4 a0 = *(const float4*)&As[t0+0][k];
    float4 a1 = *(const float4*)&As[t0+1][k];
    float4 a2 = *(const float4*)&As[t0+2][k];
    float4 a3 = *(const float4*)&As[t0+3][k];
    #pragma unroll
    for (int r=0;r<8;r++){
      float4 w = *(const float4*)(wb + (size_t)r*DMz + k);
      acc[0][r] = fmaf(a0.x,w.x, fmaf(a0.y,w.y, fmaf(a0.z,w.z, fmaf(a0.w,w.w, acc[0][r]))));
      acc[1][r] = fmaf(a1.x,w.x, fmaf(a1.y,w.y, fmaf(a1.z,w.z, fmaf(a1.w,w.w, acc[1][r]))));
      acc[2][r] = fmaf(a2.x,w.x, fmaf(a2.y,w.y, fmaf(a2.z,w.z, fmaf(a2.w,w.w, acc[2][r]))));
      acc[3][r] = fmaf(a3.x,w.x, fmaf(a3.y,w.y, fmaf(a3.z,w.z, fmaf(a3.w,w.w, acc[3][r]))));
    }
  }
  int gt = tb*TTI + t0;
  #pragma unroll
  for (int j=0;j<4;j++){
    #pragma unroll
    for (int r=0;r<8;r++){
      int c = c0 + r;
      if (c < DIz) xin[(size_t)(gt+j)*DIz + c] = acc[j][r];
      else         zb [(size_t)(gt+j)*DIz + (c-DIz)] = acc[j][r];
    }
  }
}

// ---- K3: depthwise causal conv + silu -> u
__global__ void k_conv(const float* __restrict__ xin, const float* __restrict__ cw,
                       const float* __restrict__ cb, float* __restrict__ u){
  int idx = blockIdx.x*blockDim.x + threadIdx.x;   // B*L*DI
  int d = idx % DIz;
  int l = (idx / DIz) % Lz;
  float acc = cb[d];
  #pragma unroll
  for (int k=0;k<DCz;k++){
    int ls = l - (DCz-1) + k;
    if (ls >= 0) acc += xin[idx + (ls - l)*DIz] * cw[d*DCz + k];
  }
  u[idx] = siluf(acc);
}

// ---- K4: xdbl = u @ xp_w.T (40); dt = softplus(dtr @ dt_w.T + dt_b); split Bm, Cm
__global__ void k_xproj(const float* __restrict__ u, const float* __restrict__ xp_w,
                        const float* __restrict__ dt_w, const float* __restrict__ dt_b,
                        float* __restrict__ dt, float* __restrict__ Bm, float* __restrict__ Cm){
  int tok = blockIdx.x;
  int t = threadIdx.x;           // 256
  __shared__ __align__(16) float us[DIz];
  __shared__ float xd[DTRz + 2*DSz];
  us[t] = u[tok*DIz + t];
  __syncthreads();
  if (t < 160){
    int c = t >> 2;              // 0..39
    int kg = t & 3;              // K-chunk of 64
    const float4* w  = (const float4*)(xp_w + (size_t)c*DIz + kg*64);
    const float4* u4 = (const float4*)(us + kg*64);
    float a = 0.f;
    #pragma unroll
    for (int k=0;k<16;k++){ float4 uv=u4[k], wv=w[k];
      a += uv.x*wv.x + uv.y*wv.y + uv.z*wv.z + uv.w*wv.w; }
    a += __shfl_down(a, 2);
    a += __shfl_down(a, 1);
    if (kg == 0) xd[c] = a;
  }
  __syncthreads();
  float s = dt_b[t];
  #pragma unroll
  for (int k=0;k<DTRz;k++) s += xd[k]*dt_w[(size_t)t*DTRz + k];
  dt[tok*DIz + t] = softplusf(s);
  if (t < DSz) Bm[tok*DSz + t] = xd[DTRz + t];
  else if (t < 2*DSz) Cm[tok*DSz + (t - DSz)] = xd[DTRz + DSz + (t - DSz)];
}

// ---- K5: chunk-local scan with h0=0: record P=prod(a), H=chunk result
__global__ void k_scan1(const float* __restrict__ dt, const float* __restrict__ u,
                        const float* __restrict__ Bm, const float* __restrict__ A_log,
                        float* __restrict__ P, float* __restrict__ H){
  int bid = blockIdx.x;                        // B*NCH*16
  int b  = bid / (NCH*16);
  int rem = bid % (NCH*16);
  int ch = rem / 16;
  int dg = rem % 16;
  int t = threadIdx.x;                         // 256 = 16 d x 16 s
  int dl = t >> 4, s = t & 15;
  int d = dg*16 + dl;
  float A = -expf(A_log[d*DSz + s]);
  float h = 0.f, Pp = 1.f;
  int base = b*Lz + ch*CHUNK;
  for (int tt=0; tt<CHUNK; tt+=UB){
    float dtv[UB], uv[UB], bv[UB], av[UB];
    #pragma unroll
    for (int j=0;j<UB;j++){
      int tok = base + tt + j;
      dtv[j] = dt[(size_t)tok*DIz + d];
      uv[j]  = u[(size_t)tok*DIz + d];
      bv[j]  = Bm[(size_t)tok*DSz + s];
    }
    #pragma unroll
    for (int j=0;j<UB;j++) av[j] = __expf(dtv[j]*A);
    #pragma unroll
    for (int j=0;j<UB;j++){
      h = av[j]*h + dtv[j]*uv[j]*bv[j];
      Pp *= av[j];
    }
  }
  int idx = ((ch*Bz + b)*DIz + d)*DSz + s;
  P[idx] = Pp; H[idx] = h;
}

// ---- K6: sequential combine across 32 chunks -> hstart per chunk
__global__ void k_scan2(const float* __restrict__ P, const float* __restrict__ H,
                        float* __restrict__ hstart){
  int idx = blockIdx.x*blockDim.x + threadIdx.x;   // B*DI*DS = 8192
  float h = 0.f;
  #pragma unroll
  for (int ch=0; ch<NCH; ch++){
    int j = ch*(Bz*DIz*DSz) + idx;
    hstart[j] = h;
    h = P[j]*h + H[j];
  }
}

// ---- K7: replay chunk with correct h0, produce y, gate with silu(z) -> yg
__global__ void k_scan3(const float* __restrict__ dt, const float* __restrict__ u,
                        const float* __restrict__ Bm, const float* __restrict__ Cm,
                        const float* __restrict__ z, const float* __restrict__ A_log,
                        const float* __restrict__ Dp, const float* __restrict__ hstart,
                        float* __restrict__ yg){
  int bid = blockIdx.x;
  int b  = bid / (NCH*16);
  int rem = bid % (NCH*16);
  int ch = rem / 16;
  int dg = rem % 16;
  int t = threadIdx.x;
  int dl = t >> 4, s = t & 15;
  int d = dg*16 + dl;
  float A = -expf(A_log[d*DSz + s]);
  float Dv = Dp[d];
  float h = hstart[((ch*Bz + b)*DIz + d)*DSz + s];
  int base = b*Lz + ch*CHUNK;
  for (int tt=0; tt<CHUNK; tt+=UB){
    float dtv[UB], uv[UB], bv[UB], cv[UB], av[UB], zv[UB];
    #pragma unroll
    for (int j=0;j<UB;j++){
      int tok = base + tt + j;
      dtv[j] = dt[(size_t)tok*DIz + d];
      uv[j]  = u[(size_t)tok*DIz + d];
      bv[j]  = Bm[(size_t)tok*DSz + s];
      cv[j]  = Cm[(size_t)tok*DSz + s];
      zv[j]  = z[(size_t)tok*DIz + d];
    }
    #pragma unroll
    for (int j=0;j<UB;j++) av[j] = __expf(dtv[j]*A);
    #pragma unroll
    for (int j=0;j<UB;j++){
      h = av[j]*h + dtv[j]*uv[j]*bv[j];
      float p = h*cv[j];
      p += __shfl_xor(p, 1, 16);
      p += __shfl_xor(p, 2, 16);
      p += __shfl_xor(p, 4, 16);
      p += __shfl_xor(p, 8, 16);
      if (s == 0){
        int tok = base + tt + j;
        float y = p + uv[j]*Dv;
        float g = zv[j];
        yg[(size_t)tok*DIz + d] = y * (g / (1.f + __expf(-g)));
      }
    }
  }
}

// ---- K8: hs = yg @ out_w.T   M=4096 N=128 K=256, tile 32x64, micro 1x8
__global__ void k_gemm_out(const float* __restrict__ yg, const float* __restrict__ out_w,
                           float* __restrict__ hs){
  __shared__ __align__(16) float As[32][260];
  int tb = blockIdx.x, nb = blockIdx.y, tid = threadIdx.x;
  const float4* src = (const float4*)(yg + (size_t)tb*32*DIz);
  #pragma unroll
  for (int i=tid; i<32*DIz/4; i+=256){
    int row = i >> 6, col = i & 63;
    *(float4*)&As[row][col*4] = src[i];
  }
  __syncthreads();
  int c0 = nb*64 + (tid & 7)*8;
  int t0 = tid >> 3;                 // 0..31
  const float* wb = out_w + (size_t)c0*DIz;
  float acc[8] = {};
  for (int k=0;k<DIz;k+=4){
    float4 a = *(const float4*)&As[t0][k];
    #pragma unroll
    for (int r=0;r<8;r++){
      float4 w = *(const float4*)(wb + (size_t)r*DIz + k);
      acc[r] = fmaf(a.x,w.x, fmaf(a.y,w.y, fmaf(a.z,w.z, fmaf(a.w,w.w, acc[r]))));
    }
  }
  int gt = tb*32 + t0;
  #pragma unroll
  for (int r=0;r<8;r++) hs[(size_t)gt*DMz + c0 + r] = acc[r];
}

// ---- K9: final rmsnorm(hs+res) @ head_w.T + head_b, softmax -> out (float32)
__global__ void k_head(const float* __restrict__ hs, const float* __restrict__ res,
                       const float* __restrict__ nfw, const float* __restrict__ hw,
                       const float* __restrict__ hb, float* __restrict__ out){
  int b = blockIdx.x; int t = threadIdx.x;   // 128
  __shared__ float xs[DMz];
  __shared__ float logits[NCz];
  int tok = b*Lz + (Lz-1);
  xs[t] = hs[tok*DMz + t] + res[tok*DMz + t];
  __syncthreads();
  float ss = 0.f;
  #pragma unroll
  for (int k=0;k<DMz;k++){ float v = xs[k]; ss += v*v; }
  float rs = rsqrtf(ss/(float)DMz + EPSz);
  if (t < NCz){
    float a = hb[t];
    const float* wr = hw + (size_t)t*DMz;
    for (int k=0;k<DMz;k++) a += xs[k]*rs*nfw[k]*wr[k];
    logits[t] = a;
  }
  __syncthreads();
  if (t == 0){
    float m = logits[0];
    for (int c=1;c<NCz;c++) m = fmaxf(m, logits[c]);
    float ssum = 0.f; float e[NCz];
    for (int c=0;c<NCz;c++){ e[c] = expf(logits[c]-m); ssum += e[c]; }
    for (int c=0;c<NCz;c++) out[b*NCz + c] = e[c]/ssum;
  }
}

extern "C" void kernel_launch(void* const* d_in, const int* in_sizes, int n_in,
                              void* d_out, int out_size, void* d_ws, size_t ws_size,
                              hipStream_t stream){
  const float* input_ids  = (const float*)d_in[0];
  const float* in_norm_w  = (const float*)d_in[1];
  const float* in2m_w     = (const float*)d_in[2];
  const float* in2m_b     = (const float*)d_in[3];
  const float* norm_w     = (const float*)d_in[4];
  const float* in_proj_w  = (const float*)d_in[5];
  const float* conv_w     = (const float*)d_in[6];
  const float* conv_b     = (const float*)d_in[7];
  const float* x_proj_w   = (const float*)d_in[8];
  const float* dt_proj_w  = (const float*)d_in[9];
  const float* dt_proj_b  = (const float*)d_in[10];
  const float* A_log      = (const float*)d_in[11];
  const float* D_param    = (const float*)d_in[12];
  const float* out_proj_w = (const float*)d_in[13];
  const float* norm_f_w   = (const float*)d_in[14];
  const float* head_w     = (const float*)d_in[15];
  const float* head_b     = (const float*)d_in[16];

  float* ws  = (float*)d_ws;
  float* res = ws;                  // B*L*DM   = 524288
  float* hs  = res + 524288;        // B*L*DM
  float* xin = hs  + 524288;        // B*L*DI (reused as y_gated)
  float* zb  = xin + 1048576;       // B*L*DI
  float* ub  = zb  + 1048576;       // B*L*DI
  float* dtb = ub  + 1048576;       // B*L*DI
  float* Bmb = dtb + 1048576;       // B*L*DS
  float* Cmb = Bmb + 65536;         // B*L*DS
  float* Pb  = Cmb + 65536;         // NCH*B*DI*DS = 262144
  float* Hb  = Pb  + 262144;
  float* hst = Hb  + 262144;
  float* xn  = dtb;                 // alias: xn dead before k_xproj writes dtb

  k_embed<<<Bz*Lz, DMz, 0, stream>>>(input_ids, in_norm_w, in2m_w, in2m_b, hs);
  for (int i=0;i<NLz;i++){
    k_norm<<<(Bz*Lz)/4, 256, 0, stream>>>(hs, res, norm_w + i*DMz, xn, i==0);
    k_gemm_in<<<dim3((Bz*Lz)/TTI, 4), 256, 0, stream>>>(xn, in_proj_w + (size_t)i*2*DIz*DMz, xin, zb);
    k_conv<<<(Bz*Lz*DIz)/256, 256, 0, stream>>>(xin, conv_w + i*DIz*DCz, conv_b + i*DIz, ub);
    k_xproj<<<Bz*Lz, 256, 0, stream>>>(ub, x_proj_w + (size_t)i*(DTRz+2*DSz)*DIz,
                                       dt_proj_w + (size_t)i*DIz*DTRz, dt_proj_b + i*DIz,
                                       dtb, Bmb, Cmb);
    k_scan1<<<Bz*NCH*16, 256, 0, stream>>>(dtb, ub, Bmb, A_log + i*DIz*DSz, Pb, Hb);
    k_scan2<<<(Bz*DIz*DSz)/256, 256, 0, stream>>>(Pb, Hb, hst);
    k_scan3<<<Bz*NCH*16, 256, 0, stream>>>(dtb, ub, Bmb, Cmb, zb, A_log + i*DIz*DSz,
                                           D_param + i*DIz, hst, xin);
    k_gemm_out<<<dim3((Bz*Lz)/32, 2), 256, 0, stream>>>(xin, out_proj_w + (size_t)i*DMz*DIz, hs);
  }
  k_head<<<Bz, DMz, 0, stream>>>(hs, res, norm_f_w, head_w, head_b, (float*)d_out);
}

// Round 5
// 613.594 us; speedup vs baseline: 3.2190x; 1.7323x over previous
//
#include <hip/hip_runtime.h>
#include <hip/hip_bf16.h>

// Problem constants
#define Bz   2
#define Lz   2048
#define CINz 20
#define DMz  128
#define DIz  256
#define DSz  16
#define DTRz 8
#define DCz  4
#define NLz  6
#define NCz  6
#define EPSz 1e-5f
#define CHUNK 64
#define NCH   32   // Lz / CHUNK
#define UB    8    // scan unroll batch

__device__ __forceinline__ float siluf(float x){ return x / (1.0f + expf(-x)); }
__device__ __forceinline__ float softplusf(float x){ return (x > 20.f) ? x : log1pf(expf(x)); }

// ---- K1: embed = rmsnorm(input_ids) @ in2m_w.T + b, silu -> hs (B,L,DM)
__global__ void k_embed(const float* __restrict__ ids, const float* __restrict__ nw,
                        const float* __restrict__ w, const float* __restrict__ b,
                        float* __restrict__ hs){
  int tok = blockIdx.x;          // B*L
  int t = threadIdx.x;           // DM=128
  __shared__ float xs[CINz];
  if (t < CINz) xs[t] = ids[tok*CINz + t];
  __syncthreads();
  float ss = 0.f;
  #pragma unroll
  for (int k=0;k<CINz;k++){ float v = xs[k]; ss += v*v; }
  float rs = rsqrtf(ss/(float)CINz + EPSz);
  float acc = b[t];
  const float* wr = w + (size_t)t*CINz;
  #pragma unroll
  for (int k=0;k<CINz;k++) acc += xs[k]*rs*nw[k]*wr[k];
  hs[tok*DMz + t] = siluf(acc);
}

// ---- K2a: res update + rmsnorm*norm_w -> xn (4 tokens/block). two: hs = hs0+hs1
__global__ void k_norm(const float* __restrict__ hs0, const float* __restrict__ hs1,
                       float* __restrict__ res, const float* __restrict__ norm_w,
                       float* __restrict__ xn, int first){
  int tok = blockIdx.x*4 + (threadIdx.x >> 6);
  int lane = threadIdx.x & 63;
  size_t off = (size_t)tok*DMz + lane*2;
  float2 h = *(const float2*)(hs0 + off);
  float2 r2;
  if (first){ r2 = h; }
  else {
    float2 h1 = *(const float2*)(hs1 + off);
    float2 rr = *(const float2*)(res + off);
    r2 = make_float2(h.x+h1.x+rr.x, h.y+h1.y+rr.y);
  }
  *(float2*)(res + off) = r2;
  float ss = r2.x*r2.x + r2.y*r2.y;
  #pragma unroll
  for (int off2=32; off2; off2>>=1) ss += __shfl_xor(ss, off2);
  float rs = rsqrtf(ss*(1.0f/DMz) + EPSz);
  float2 nw = *(const float2*)(norm_w + lane*2);
  *(float2*)(xn + off) = make_float2(r2.x*rs*nw.x, r2.y*rs*nw.y);
}

// ---- K2b: xz = xn @ in_w.T   M=4096 N=512 K=128; tile 32x64, grid (128,8)
__global__ void k_gemm_in(const float* __restrict__ xn, const float* __restrict__ in_w,
                          float* __restrict__ xin, float* __restrict__ zb){
  __shared__ __align__(16) float As[32][132];
  __shared__ __align__(16) float Ws[64][132];
  int tb = blockIdx.x, nb = blockIdx.y, tid = threadIdx.x;
  // stage A: 32 rows x 128 = 1024 float4
  #pragma unroll
  for (int i=tid; i<32*DMz/4; i+=256){
    int row = i >> 5, c4 = i & 31;
    *(float4*)&As[row][c4*4] = *(const float4*)(xn + (size_t)(tb*32+row)*DMz + c4*4);
  }
  // stage W: 64 rows x 128 = 2048 float4
  #pragma unroll
  for (int i=tid; i<64*DMz/4; i+=256){
    int row = i >> 5, c4 = i & 31;
    *(float4*)&Ws[row][c4*4] = *(const float4*)(in_w + (size_t)(nb*64+row)*DMz + c4*4);
  }
  __syncthreads();
  int tp = tid >> 4;      // token pair 0..15
  int cl = tid & 15;      // col lane; cols cl+16j
  float acc[2][4] = {};
  for (int k=0;k<DMz;k+=4){
    float4 a0 = *(const float4*)&As[tp*2+0][k];
    float4 a1 = *(const float4*)&As[tp*2+1][k];
    #pragma unroll
    for (int j=0;j<4;j++){
      float4 w = *(const float4*)&Ws[cl+16*j][k];
      acc[0][j] = fmaf(a0.x,w.x, fmaf(a0.y,w.y, fmaf(a0.z,w.z, fmaf(a0.w,w.w, acc[0][j]))));
      acc[1][j] = fmaf(a1.x,w.x, fmaf(a1.y,w.y, fmaf(a1.z,w.z, fmaf(a1.w,w.w, acc[1][j]))));
    }
  }
  #pragma unroll
  for (int i=0;i<2;i++){
    int gt = tb*32 + tp*2 + i;
    #pragma unroll
    for (int j=0;j<4;j++){
      int c = nb*64 + cl + 16*j;
      if (c < DIz) xin[(size_t)gt*DIz + c] = acc[i][j];
      else         zb [(size_t)gt*DIz + (c-DIz)] = acc[i][j];
    }
  }
}

// ---- K3: depthwise causal conv + silu -> u
__global__ void k_conv(const float* __restrict__ xin, const float* __restrict__ cw,
                       const float* __restrict__ cb, float* __restrict__ u){
  int idx = blockIdx.x*blockDim.x + threadIdx.x;   // B*L*DI
  int d = idx % DIz;
  int l = (idx / DIz) % Lz;
  float acc = cb[d];
  #pragma unroll
  for (int k=0;k<DCz;k++){
    int ls = l - (DCz-1) + k;
    if (ls >= 0) acc += xin[idx + (ls - l)*DIz] * cw[d*DCz + k];
  }
  u[idx] = siluf(acc);
}

// ---- K4: xdbl = u @ xp_w.T (40); dt = softplus(dtr @ dt_w.T + dt_b); split Bm, Cm
__global__ void k_xproj(const float* __restrict__ u, const float* __restrict__ xp_w,
                        const float* __restrict__ dt_w, const float* __restrict__ dt_b,
                        float* __restrict__ dt, float* __restrict__ Bm, float* __restrict__ Cm){
  int tok = blockIdx.x;
  int t = threadIdx.x;           // 256
  __shared__ __align__(16) float us[DIz];
  __shared__ float xd[DTRz + 2*DSz];
  us[t] = u[tok*DIz + t];
  __syncthreads();
  if (t < 160){
    int c = t >> 2;              // 0..39
    int kg = t & 3;              // K-chunk of 64
    const float4* w  = (const float4*)(xp_w + (size_t)c*DIz + kg*64);
    const float4* u4 = (const float4*)(us + kg*64);
    float a = 0.f;
    #pragma unroll
    for (int k=0;k<16;k++){ float4 uv=u4[k], wv=w[k];
      a += uv.x*wv.x + uv.y*wv.y + uv.z*wv.z + uv.w*wv.w; }
    a += __shfl_down(a, 2);
    a += __shfl_down(a, 1);
    if (kg == 0) xd[c] = a;
  }
  __syncthreads();
  float s = dt_b[t];
  #pragma unroll
  for (int k=0;k<DTRz;k++) s += xd[k]*dt_w[(size_t)t*DTRz + k];
  dt[tok*DIz + t] = softplusf(s);
  if (t < DSz) Bm[tok*DSz + t] = xd[DTRz + t];
  else if (t < 2*DSz) Cm[tok*DSz + (t - DSz)] = xd[DTRz + DSz + (t - DSz)];
}

// ---- K5: chunk-local scan with h0=0: record P=prod(a), H=chunk result
__global__ void k_scan1(const float* __restrict__ dt, const float* __restrict__ u,
                        const float* __restrict__ Bm, const float* __restrict__ A_log,
                        float* __restrict__ P, float* __restrict__ H){
  int bid = blockIdx.x;                        // B*NCH*16
  int b  = bid / (NCH*16);
  int rem = bid % (NCH*16);
  int ch = rem / 16;
  int dg = rem % 16;
  int t = threadIdx.x;                         // 256 = 16 d x 16 s
  int dl = t >> 4, s = t & 15;
  int d = dg*16 + dl;
  float A = -expf(A_log[d*DSz + s]);
  float h = 0.f, Pp = 1.f;
  int base = b*Lz + ch*CHUNK;
  for (int tt=0; tt<CHUNK; tt+=UB){
    float dtv[UB], uv[UB], bv[UB], av[UB];
    #pragma unroll
    for (int j=0;j<UB;j++){
      int tok = base + tt + j;
      dtv[j] = dt[(size_t)tok*DIz + d];
      uv[j]  = u[(size_t)tok*DIz + d];
      bv[j]  = Bm[(size_t)tok*DSz + s];
    }
    #pragma unroll
    for (int j=0;j<UB;j++) av[j] = __expf(dtv[j]*A);
    #pragma unroll
    for (int j=0;j<UB;j++){
      h = av[j]*h + dtv[j]*uv[j]*bv[j];
      Pp *= av[j];
    }
  }
  int idx = ((ch*Bz + b)*DIz + d)*DSz + s;
  P[idx] = Pp; H[idx] = h;
}

// ---- K6: sequential combine across 32 chunks -> hstart per chunk
__global__ void k_scan2(const float* __restrict__ P, const float* __restrict__ H,
                        float* __restrict__ hstart){
  int idx = blockIdx.x*blockDim.x + threadIdx.x;   // B*DI*DS = 8192
  float h = 0.f;
  #pragma unroll
  for (int ch=0; ch<NCH; ch++){
    int j = ch*(Bz*DIz*DSz) + idx;
    hstart[j] = h;
    h = P[j]*h + H[j];
  }
}

// ---- K7: replay chunk with correct h0, produce y, gate with silu(z) -> yg
__global__ void k_scan3(const float* __restrict__ dt, const float* __restrict__ u,
                        const float* __restrict__ Bm, const float* __restrict__ Cm,
                        const float* __restrict__ z, const float* __restrict__ A_log,
                        const float* __restrict__ Dp, const float* __restrict__ hstart,
                        float* __restrict__ yg){
  int bid = blockIdx.x;
  int b  = bid / (NCH*16);
  int rem = bid % (NCH*16);
  int ch = rem / 16;
  int dg = rem % 16;
  int t = threadIdx.x;
  int dl = t >> 4, s = t & 15;
  int d = dg*16 + dl;
  float A = -expf(A_log[d*DSz + s]);
  float Dv = Dp[d];
  float h = hstart[((ch*Bz + b)*DIz + d)*DSz + s];
  int base = b*Lz + ch*CHUNK;
  for (int tt=0; tt<CHUNK; tt+=UB){
    float dtv[UB], uv[UB], bv[UB], cv[UB], av[UB], zv[UB];
    #pragma unroll
    for (int j=0;j<UB;j++){
      int tok = base + tt + j;
      dtv[j] = dt[(size_t)tok*DIz + d];
      uv[j]  = u[(size_t)tok*DIz + d];
      bv[j]  = Bm[(size_t)tok*DSz + s];
      cv[j]  = Cm[(size_t)tok*DSz + s];
      zv[j]  = z[(size_t)tok*DIz + d];
    }
    #pragma unroll
    for (int j=0;j<UB;j++) av[j] = __expf(dtv[j]*A);
    #pragma unroll
    for (int j=0;j<UB;j++){
      h = av[j]*h + dtv[j]*uv[j]*bv[j];
      float p = h*cv[j];
      p += __shfl_xor(p, 1, 16);
      p += __shfl_xor(p, 2, 16);
      p += __shfl_xor(p, 4, 16);
      p += __shfl_xor(p, 8, 16);
      if (s == 0){
        int tok = base + tt + j;
        float y = p + uv[j]*Dv;
        float g = zv[j];
        yg[(size_t)tok*DIz + d] = y * (g / (1.f + __expf(-g)));
      }
    }
  }
}

// ---- K8: hs_part[z] = yg @ out_w.T (K-half z)  M=4096 N=128 K=256; grid (128,2,2)
__global__ void k_gemm_out(const float* __restrict__ yg, const float* __restrict__ out_w,
                           float* __restrict__ hs0, float* __restrict__ hs1){
  __shared__ __align__(16) float As[32][132];
  __shared__ __align__(16) float Ws[64][132];
  int tb = blockIdx.x, nb = blockIdx.y, kz = blockIdx.z, tid = threadIdx.x;
  int k0 = kz*128;
  #pragma unroll
  for (int i=tid; i<32*128/4; i+=256){
    int row = i >> 5, c4 = i & 31;
    *(float4*)&As[row][c4*4] = *(const float4*)(yg + (size_t)(tb*32+row)*DIz + k0 + c4*4);
  }
  #pragma unroll
  for (int i=tid; i<64*128/4; i+=256){
    int row = i >> 5, c4 = i & 31;
    *(float4*)&Ws[row][c4*4] = *(const float4*)(out_w + (size_t)(nb*64+row)*DIz + k0 + c4*4);
  }
  __syncthreads();
  int tp = tid >> 4;
  int cl = tid & 15;
  float acc[2][4] = {};
  for (int k=0;k<128;k+=4){
    float4 a0 = *(const float4*)&As[tp*2+0][k];
    float4 a1 = *(const float4*)&As[tp*2+1][k];
    #pragma unroll
    for (int j=0;j<4;j++){
      float4 w = *(const float4*)&Ws[cl+16*j][k];
      acc[0][j] = fmaf(a0.x,w.x, fmaf(a0.y,w.y, fmaf(a0.z,w.z, fmaf(a0.w,w.w, acc[0][j]))));
      acc[1][j] = fmaf(a1.x,w.x, fmaf(a1.y,w.y, fmaf(a1.z,w.z, fmaf(a1.w,w.w, acc[1][j]))));
    }
  }
  float* dst = kz ? hs1 : hs0;
  #pragma unroll
  for (int i=0;i<2;i++){
    int gt = tb*32 + tp*2 + i;
    #pragma unroll
    for (int j=0;j<4;j++){
      dst[(size_t)gt*DMz + nb*64 + cl + 16*j] = acc[i][j];
    }
  }
}

// ---- K9: final rmsnorm(hs0+hs1+res) @ head_w.T + head_b, softmax -> out (float32)
__global__ void k_head(const float* __restrict__ hs0, const float* __restrict__ hs1,
                       const float* __restrict__ res,
                       const float* __restrict__ nfw, const float* __restrict__ hw,
                       const float* __restrict__ hb, float* __restrict__ out){
  int b = blockIdx.x; int t = threadIdx.x;   // 128
  __shared__ float xs[DMz];
  __shared__ float logits[NCz];
  int tok = b*Lz + (Lz-1);
  xs[t] = hs0[tok*DMz + t] + hs1[tok*DMz + t] + res[tok*DMz + t];
  __syncthreads();
  float ss = 0.f;
  #pragma unroll
  for (int k=0;k<DMz;k++){ float v = xs[k]; ss += v*v; }
  float rs = rsqrtf(ss/(float)DMz + EPSz);
  if (t < NCz){
    float a = hb[t];
    const float* wr = hw + (size_t)t*DMz;
    for (int k=0;k<DMz;k++) a += xs[k]*rs*nfw[k]*wr[k];
    logits[t] = a;
  }
  __syncthreads();
  if (t == 0){
    float m = logits[0];
    for (int c=1;c<NCz;c++) m = fmaxf(m, logits[c]);
    float ssum = 0.f; float e[NCz];
    for (int c=0;c<NCz;c++){ e[c] = expf(logits[c]-m); ssum += e[c]; }
    for (int c=0;c<NCz;c++) out[b*NCz + c] = e[c]/ssum;
  }
}

extern "C" void kernel_launch(void* const* d_in, const int* in_sizes, int n_in,
                              void* d_out, int out_size, void* d_ws, size_t ws_size,
                              hipStream_t stream){
  const float* input_ids  = (const float*)d_in[0];
  const float* in_norm_w  = (const float*)d_in[1];
  const float* in2m_w     = (const float*)d_in[2];
  const float* in2m_b     = (const float*)d_in[3];
  const float* norm_w     = (const float*)d_in[4];
  const float* in_proj_w  = (const float*)d_in[5];
  const float* conv_w     = (const float*)d_in[6];
  const float* conv_b     = (const float*)d_in[7];
  const float* x_proj_w   = (const float*)d_in[8];
  const float* dt_proj_w  = (const float*)d_in[9];
  const float* dt_proj_b  = (const float*)d_in[10];
  const float* A_log      = (const float*)d_in[11];
  const float* D_param    = (const float*)d_in[12];
  const float* out_proj_w = (const float*)d_in[13];
  const float* norm_f_w   = (const float*)d_in[14];
  const float* head_w     = (const float*)d_in[15];
  const float* head_b     = (const float*)d_in[16];

  float* ws  = (float*)d_ws;
  float* res = ws;                  // B*L*DM   = 524288
  float* hs  = res + 524288;        // B*L*DM (hs0)
  float* xin = hs  + 524288;        // B*L*DI (reused as y_gated)
  float* zb  = xin + 1048576;       // B*L*DI
  float* ub  = zb  + 1048576;       // B*L*DI
  float* dtb = ub  + 1048576;       // B*L*DI
  float* Bmb = dtb + 1048576;       // B*L*DS
  float* Cmb = Bmb + 65536;         // B*L*DS
  float* Pb  = Cmb + 65536;         // NCH*B*DI*DS = 262144
  float* Hb  = Pb  + 262144;        // 262144
  float* hst = Hb  + 262144;        // 262144
  float* xn  = dtb;                 // alias: xn dead before k_xproj writes dtb
  float* hs1 = Pb;                  // alias: Pb+Hb = 524288 floats, dead after k_scan2/3,
                                    // consumed by k_norm before k_scan1 rewrites Pb

  k_embed<<<Bz*Lz, DMz, 0, stream>>>(input_ids, in_norm_w, in2m_w, in2m_b, hs);
  for (int i=0;i<NLz;i++){
    k_norm<<<(Bz*Lz)/4, 256, 0, stream>>>(hs, hs1, res, norm_w + i*DMz, xn, i==0);
    k_gemm_in<<<dim3(128, 8), 256, 0, stream>>>(xn, in_proj_w + (size_t)i*2*DIz*DMz, xin, zb);
    k_conv<<<(Bz*Lz*DIz)/256, 256, 0, stream>>>(xin, conv_w + i*DIz*DCz, conv_b + i*DIz, ub);
    k_xproj<<<Bz*Lz, 256, 0, stream>>>(ub, x_proj_w + (size_t)i*(DTRz+2*DSz)*DIz,
                                       dt_proj_w + (size_t)i*DIz*DTRz, dt_proj_b + i*DIz,
                                       dtb, Bmb, Cmb);
    k_scan1<<<Bz*NCH*16, 256, 0, stream>>>(dtb, ub, Bmb, A_log + i*DIz*DSz, Pb, Hb);
    k_scan2<<<(Bz*DIz*DSz)/256, 256, 0, stream>>>(Pb, Hb, hst);
    k_scan3<<<Bz*NCH*16, 256, 0, stream>>>(dtb, ub, Bmb, Cmb, zb, A_log + i*DIz*DSz,
                                           D_param + i*DIz, hst, xin);
    k_gemm_out<<<dim3(128, 2, 2), 256, 0, stream>>>(xin, out_proj_w + (size_t)i*DMz*DIz, hs, hs1);
  }
  k_head<<<Bz, DMz, 0, stream>>>(hs, hs1, res, norm_f_w, head_w, head_b, (float*)d_out);
}

// Round 6
// 503.237 us; speedup vs baseline: 3.9249x; 1.2193x over previous
//
#include <hip/hip_runtime.h>
#include <hip/hip_bf16.h>

// Problem constants
#define Bz   2
#define Lz   2048
#define CINz 20
#define DMz  128
#define DIz  256
#define DSz  16
#define DTRz 8
#define DCz  4
#define NLz  6
#define NCz  6
#define EPSz 1e-5f
#define CHUNK 8
#define NCH   256   // Lz / CHUNK
#define XT    16    // tokens per xprojc block

__device__ __forceinline__ float siluf(float x){ return x / (1.0f + expf(-x)); }
__device__ __forceinline__ float softplusf(float x){ return (x > 20.f) ? x : log1pf(expf(x)); }

// ---- K1: embed = rmsnorm(input_ids) @ in2m_w.T + b, silu -> hs (B,L,DM)
__global__ void k_embed(const float* __restrict__ ids, const float* __restrict__ nw,
                        const float* __restrict__ w, const float* __restrict__ b,
                        float* __restrict__ hs){
  int tok = blockIdx.x;          // B*L
  int t = threadIdx.x;           // DM=128
  __shared__ float xs[CINz];
  if (t < CINz) xs[t] = ids[tok*CINz + t];
  __syncthreads();
  float ss = 0.f;
  #pragma unroll
  for (int k=0;k<CINz;k++){ float v = xs[k]; ss += v*v; }
  float rs = rsqrtf(ss/(float)CINz + EPSz);
  float acc = b[t];
  const float* wr = w + (size_t)t*CINz;
  #pragma unroll
  for (int k=0;k<CINz;k++) acc += xs[k]*rs*nw[k]*wr[k];
  hs[tok*DMz + t] = siluf(acc);
}

// ---- K2a: res update + rmsnorm*norm_w -> xn (4 tokens/block). hs = hs0+hs1
__global__ void k_norm(const float* __restrict__ hs0, const float* __restrict__ hs1,
                       float* __restrict__ res, const float* __restrict__ norm_w,
                       float* __restrict__ xn, int first){
  int tok = blockIdx.x*4 + (threadIdx.x >> 6);
  int lane = threadIdx.x & 63;
  size_t off = (size_t)tok*DMz + lane*2;
  float2 h = *(const float2*)(hs0 + off);
  float2 r2;
  if (first){ r2 = h; }
  else {
    float2 h1 = *(const float2*)(hs1 + off);
    float2 rr = *(const float2*)(res + off);
    r2 = make_float2(h.x+h1.x+rr.x, h.y+h1.y+rr.y);
  }
  *(float2*)(res + off) = r2;
  float ss = r2.x*r2.x + r2.y*r2.y;
  #pragma unroll
  for (int off2=32; off2; off2>>=1) ss += __shfl_xor(ss, off2);
  float rs = rsqrtf(ss*(1.0f/DMz) + EPSz);
  float2 nw = *(const float2*)(norm_w + lane*2);
  *(float2*)(xn + off) = make_float2(r2.x*rs*nw.x, r2.y*rs*nw.y);
}

// ---- K2b: xz = xn @ in_w.T   M=4096 N=512 K=128; tile 32x64, grid (128,8)
__global__ void k_gemm_in(const float* __restrict__ xn, const float* __restrict__ in_w,
                          float* __restrict__ xin, float* __restrict__ zb){
  __shared__ __align__(16) float As[32][132];
  __shared__ __align__(16) float Ws[64][132];
  int tb = blockIdx.x, nb = blockIdx.y, tid = threadIdx.x;
  #pragma unroll
  for (int i=tid; i<32*DMz/4; i+=256){
    int row = i >> 5, c4 = i & 31;
    *(float4*)&As[row][c4*4] = *(const float4*)(xn + (size_t)(tb*32+row)*DMz + c4*4);
  }
  #pragma unroll
  for (int i=tid; i<64*DMz/4; i+=256){
    int row = i >> 5, c4 = i & 31;
    *(float4*)&Ws[row][c4*4] = *(const float4*)(in_w + (size_t)(nb*64+row)*DMz + c4*4);
  }
  __syncthreads();
  int tp = tid >> 4;      // token pair 0..15
  int cl = tid & 15;      // col lane; cols cl+16j
  float acc[2][4] = {};
  for (int k=0;k<DMz;k+=4){
    float4 a0 = *(const float4*)&As[tp*2+0][k];
    float4 a1 = *(const float4*)&As[tp*2+1][k];
    #pragma unroll
    for (int j=0;j<4;j++){
      float4 w = *(const float4*)&Ws[cl+16*j][k];
      acc[0][j] = fmaf(a0.x,w.x, fmaf(a0.y,w.y, fmaf(a0.z,w.z, fmaf(a0.w,w.w, acc[0][j]))));
      acc[1][j] = fmaf(a1.x,w.x, fmaf(a1.y,w.y, fmaf(a1.z,w.z, fmaf(a1.w,w.w, acc[1][j]))));
    }
  }
  #pragma unroll
  for (int i=0;i<2;i++){
    int gt = tb*32 + tp*2 + i;
    #pragma unroll
    for (int j=0;j<4;j++){
      int c = nb*64 + cl + 16*j;
      if (c < DIz) xin[(size_t)gt*DIz + c] = acc[i][j];
      else         zb [(size_t)gt*DIz + (c-DIz)] = acc[i][j];
    }
  }
}

// ---- K4: fused conv+silu + xproj + dt for a 16-token tile
__global__ void k_xprojc(const float* __restrict__ xin, const float* __restrict__ cw,
                         const float* __restrict__ cb, const float* __restrict__ xp_w,
                         const float* __restrict__ dt_w, const float* __restrict__ dt_b,
                         float* __restrict__ dt, float* __restrict__ Bm, float* __restrict__ Cm){
  __shared__ __align__(16) float xs[XT+3][DIz];   // 19.4 KB
  __shared__ __align__(16) float us[XT][DIz];     // 16 KB
  __shared__ float xd[XT][40];
  int tb = blockIdx.x;           // 0..255
  int b  = tb >> 7;              // / (Lz/XT)
  int l0 = (tb & 127) * XT;
  int tid = threadIdx.x;
  // stage xin rows l0-3 .. l0+15 (zero-pad l<0)
  for (int i = tid; i < (XT+3)*(DIz/4); i += 256){
    int r = i >> 6, c4 = (i & 63)*4;
    int l = l0 - 3 + r;
    float4 v = make_float4(0,0,0,0);
    if (l >= 0) v = *(const float4*)(xin + ((size_t)(b*Lz + l))*DIz + c4);
    *(float4*)&xs[r][c4] = v;
  }
  __syncthreads();
  // conv+silu into us: thread d = tid
  {
    int d = tid;
    float c0 = cw[d*DCz+0], c1 = cw[d*DCz+1], c2 = cw[d*DCz+2], c3 = cw[d*DCz+3];
    float bb = cb[d];
    #pragma unroll
    for (int tt=0; tt<XT; tt++){
      float acc = bb + xs[tt][d]*c0 + xs[tt+1][d]*c1 + xs[tt+2][d]*c2 + xs[tt+3][d]*c3;
      us[tt][d] = acc / (1.f + __expf(-acc));
    }
  }
  __syncthreads();
  // xdbl: 160 threads: c = t>>2 (0..39), kg = t&3; k = kg*4 + m*16 + j
  if (tid < 160){
    int c = tid >> 2, kg = tid & 3;
    const float* wrow = xp_w + (size_t)c*DIz;
    float4 wreg[16];
    #pragma unroll
    for (int m=0;m<16;m++) wreg[m] = *(const float4*)(wrow + kg*4 + m*16);
    #pragma unroll
    for (int tt=0; tt<XT; tt++){
      float a = 0.f;
      #pragma unroll
      for (int m=0;m<16;m++){
        float4 uv = *(const float4*)&us[tt][kg*4 + m*16];
        float4 wv = wreg[m];
        a += uv.x*wv.x + uv.y*wv.y + uv.z*wv.z + uv.w*wv.w;
      }
      a += __shfl_down(a, 2);
      a += __shfl_down(a, 1);
      if (kg == 0) xd[tt][c] = a;
    }
  }
  __syncthreads();
  // dt: thread d for all 16 tokens; Bm/Cm split writes
  {
    int d = tid;
    float w0[DTRz];
    #pragma unroll
    for (int k=0;k<DTRz;k++) w0[k] = dt_w[(size_t)d*DTRz + k];
    float bias = dt_b[d];
    #pragma unroll
    for (int tt=0; tt<XT; tt++){
      float s = bias;
      #pragma unroll
      for (int k=0;k<DTRz;k++) s += xd[tt][k]*w0[k];
      dt[((size_t)(b*Lz + l0 + tt))*DIz + d] = softplusf(s);
    }
    int tt = tid >> 4, s2 = tid & 15;
    Bm[((size_t)(b*Lz + l0 + tt))*DSz + s2] = xd[tt][DTRz + s2];
    Cm[((size_t)(b*Lz + l0 + tt))*DSz + s2] = xd[tt][DTRz + DSz + s2];
  }
}

// ---- K5: chunk-local scan, thread-per-d, 16 states in regs; conv recomputed inline
__global__ void k_scan1(const float* __restrict__ xin, const float* __restrict__ dt,
                        const float* __restrict__ Bm,
                        const float* __restrict__ cw, const float* __restrict__ cb,
                        const float* __restrict__ A_log,
                        float* __restrict__ P, float* __restrict__ H){
  int bid = blockIdx.x;           // Bz*NCH = 512
  int b = bid >> 8;
  int ch = bid & (NCH-1);
  int d = threadIdx.x;
  __shared__ float B_l[CHUNK][DSz];
  if (threadIdx.x < CHUNK*DSz){
    int tt = threadIdx.x >> 4, s = threadIdx.x & 15;
    B_l[tt][s] = Bm[((size_t)(b*Lz + ch*CHUNK + tt))*DSz + s];
  }
  float Av[DSz];
  #pragma unroll
  for (int q=0;q<4;q++){
    float4 al = *(const float4*)(A_log + d*DSz + q*4);
    Av[q*4+0] = -__expf(al.x); Av[q*4+1] = -__expf(al.y);
    Av[q*4+2] = -__expf(al.z); Av[q*4+3] = -__expf(al.w);
  }
  float c0=cw[d*DCz],c1=cw[d*DCz+1],c2=cw[d*DCz+2],c3=cw[d*DCz+3], bb=cb[d];
  int l0 = ch*CHUNK;
  size_t base = (size_t)(b*Lz + l0)*DIz + d;
  float w0=0.f, w1=0.f, w2=0.f;
  if (l0 >= 3){ w0 = xin[base - 3*DIz]; w1 = xin[base - 2*DIz]; w2 = xin[base - DIz]; }
  __syncthreads();
  float h[DSz], Pp[DSz];
  #pragma unroll
  for (int s=0;s<DSz;s++){ h[s]=0.f; Pp[s]=1.f; }
  #pragma unroll
  for (int tt=0; tt<CHUNK; tt++){
    float w3  = xin[base + (size_t)tt*DIz];
    float dtv = dt[base + (size_t)tt*DIz];
    float uacc = bb + w0*c0 + w1*c1 + w2*c2 + w3*c3;
    float u = uacc / (1.f + __expf(-uacc));
    w0=w1; w1=w2; w2=w3;
    float x = dtv*u;
    #pragma unroll
    for (int s=0;s<DSz;s++){
      float a = __expf(dtv*Av[s]);
      h[s] = a*h[s] + x*B_l[tt][s];
      Pp[s] *= a;
    }
  }
  size_t o = ((size_t)(ch*Bz + b)*DIz + d)*DSz;
  #pragma unroll
  for (int q=0;q<4;q++){
    *(float4*)(P + o + q*4) = make_float4(Pp[q*4],Pp[q*4+1],Pp[q*4+2],Pp[q*4+3]);
    *(float4*)(H + o + q*4) = make_float4(h[q*4],h[q*4+1],h[q*4+2],h[q*4+3]);
  }
}

// ---- K6: sequential combine across NCH chunks -> hstart per chunk
__global__ void k_scan2(const float* __restrict__ P, const float* __restrict__ H,
                        float* __restrict__ hstart){
  int idx = blockIdx.x*256 + threadIdx.x;   // B*DI*DS = 8192
  float h = 0.f;
  for (int c0=0; c0<NCH; c0+=32){
    float p[32], q[32];
    #pragma unroll
    for (int j=0;j<32;j++){
      int o = (c0+j)*(Bz*DIz*DSz) + idx;
      p[j] = P[o]; q[j] = H[o];
    }
    #pragma unroll
    for (int j=0;j<32;j++){
      int o = (c0+j)*(Bz*DIz*DSz) + idx;
      hstart[o] = h;
      h = p[j]*h + q[j];
    }
  }
}

// ---- K7: replay chunk with correct h0, produce y, gate -> yg
__global__ void k_scan3(const float* __restrict__ xin, const float* __restrict__ dt,
                        const float* __restrict__ Bm, const float* __restrict__ Cm,
                        const float* __restrict__ z,
                        const float* __restrict__ cw, const float* __restrict__ cb,
                        const float* __restrict__ A_log, const float* __restrict__ Dp,
                        const float* __restrict__ hstart, float* __restrict__ yg){
  int bid = blockIdx.x;
  int b = bid >> 8;
  int ch = bid & (NCH-1);
  int d = threadIdx.x;
  __shared__ float B_l[CHUNK][DSz], C_l[CHUNK][DSz];
  if (threadIdx.x < CHUNK*DSz){
    int tt = threadIdx.x >> 4, s = threadIdx.x & 15;
    B_l[tt][s] = Bm[((size_t)(b*Lz + ch*CHUNK + tt))*DSz + s];
  } else if (threadIdx.x < 2*CHUNK*DSz){
    int t2 = threadIdx.x - CHUNK*DSz;
    int tt = t2 >> 4, s = t2 & 15;
    C_l[tt][s] = Cm[((size_t)(b*Lz + ch*CHUNK + tt))*DSz + s];
  }
  float Av[DSz];
  #pragma unroll
  for (int q=0;q<4;q++){
    float4 al = *(const float4*)(A_log + d*DSz + q*4);
    Av[q*4+0] = -__expf(al.x); Av[q*4+1] = -__expf(al.y);
    Av[q*4+2] = -__expf(al.z); Av[q*4+3] = -__expf(al.w);
  }
  float c0=cw[d*DCz],c1=cw[d*DCz+1],c2=cw[d*DCz+2],c3=cw[d*DCz+3], bb=cb[d];
  float Dv = Dp[d];
  int l0 = ch*CHUNK;
  size_t base = (size_t)(b*Lz + l0)*DIz + d;
  float w0=0.f, w1=0.f, w2=0.f;
  if (l0 >= 3){ w0 = xin[base - 3*DIz]; w1 = xin[base - 2*DIz]; w2 = xin[base - DIz]; }
  float h[DSz];
  {
    size_t o = ((size_t)(ch*Bz + b)*DIz + d)*DSz;
    #pragma unroll
    for (int q=0;q<4;q++){
      float4 hv = *(const float4*)(hstart + o + q*4);
      h[q*4+0]=hv.x; h[q*4+1]=hv.y; h[q*4+2]=hv.z; h[q*4+3]=hv.w;
    }
  }
  __syncthreads();
  #pragma unroll
  for (int tt=0; tt<CHUNK; tt++){
    float w3  = xin[base + (size_t)tt*DIz];
    float dtv = dt[base + (size_t)tt*DIz];
    float zv  = z[base + (size_t)tt*DIz];
    float uacc = bb + w0*c0 + w1*c1 + w2*c2 + w3*c3;
    float u = uacc / (1.f + __expf(-uacc));
    w0=w1; w1=w2; w2=w3;
    float x = dtv*u;
    float y = 0.f;
    #pragma unroll
    for (int s=0;s<DSz;s++){
      float a = __expf(dtv*Av[s]);
      h[s] = a*h[s] + x*B_l[tt][s];
      y += h[s]*C_l[tt][s];
    }
    float yv = y + u*Dv;
    yg[base + (size_t)tt*DIz] = yv * (zv / (1.f + __expf(-zv)));
  }
}

// ---- K8: hs_part[kz] = yg @ out_w.T  M=4096 N=128 K=256; grid (128,2,2)
__global__ void k_gemm_out(const float* __restrict__ yg, const float* __restrict__ out_w,
                           float* __restrict__ hs0, float* __restrict__ hs1){
  __shared__ __align__(16) float As[32][132];
  __shared__ __align__(16) float Ws[64][132];
  int tb = blockIdx.x, nb = blockIdx.y, kz = blockIdx.z, tid = threadIdx.x;
  int k0 = kz*128;
  #pragma unroll
  for (int i=tid; i<32*128/4; i+=256){
    int row = i >> 5, c4 = i & 31;
    *(float4*)&As[row][c4*4] = *(const float4*)(yg + (size_t)(tb*32+row)*DIz + k0 + c4*4);
  }
  #pragma unroll
  for (int i=tid; i<64*128/4; i+=256){
    int row = i >> 5, c4 = i & 31;
    *(float4*)&Ws[row][c4*4] = *(const float4*)(out_w + (size_t)(nb*64+row)*DIz + k0 + c4*4);
  }
  __syncthreads();
  int tp = tid >> 4;
  int cl = tid & 15;
  float acc[2][4] = {};
  for (int k=0;k<128;k+=4){
    float4 a0 = *(const float4*)&As[tp*2+0][k];
    float4 a1 = *(const float4*)&As[tp*2+1][k];
    #pragma unroll
    for (int j=0;j<4;j++){
      float4 w = *(const float4*)&Ws[cl+16*j][k];
      acc[0][j] = fmaf(a0.x,w.x, fmaf(a0.y,w.y, fmaf(a0.z,w.z, fmaf(a0.w,w.w, acc[0][j]))));
      acc[1][j] = fmaf(a1.x,w.x, fmaf(a1.y,w.y, fmaf(a1.z,w.z, fmaf(a1.w,w.w, acc[1][j]))));
    }
  }
  float* dst = kz ? hs1 : hs0;
  #pragma unroll
  for (int i=0;i<2;i++){
    int gt = tb*32 + tp*2 + i;
    #pragma unroll
    for (int j=0;j<4;j++){
      dst[(size_t)gt*DMz + nb*64 + cl + 16*j] = acc[i][j];
    }
  }
}

// ---- K9: final rmsnorm(hs0+hs1+res) @ head_w.T + head_b, softmax -> out
__global__ void k_head(const float* __restrict__ hs0, const float* __restrict__ hs1,
                       const float* __restrict__ res,
                       const float* __restrict__ nfw, const float* __restrict__ hw,
                       const float* __restrict__ hb, float* __restrict__ out){
  int b = blockIdx.x; int t = threadIdx.x;   // 128
  __shared__ float xs[DMz];
  __shared__ float logits[NCz];
  int tok = b*Lz + (Lz-1);
  xs[t] = hs0[tok*DMz + t] + hs1[tok*DMz + t] + res[tok*DMz + t];
  __syncthreads();
  float ss = 0.f;
  #pragma unroll
  for (int k=0;k<DMz;k++){ float v = xs[k]; ss += v*v; }
  float rs = rsqrtf(ss/(float)DMz + EPSz);
  if (t < NCz){
    float a = hb[t];
    const float* wr = hw + (size_t)t*DMz;
    for (int k=0;k<DMz;k++) a += xs[k]*rs*nfw[k]*wr[k];
    logits[t] = a;
  }
  __syncthreads();
  if (t == 0){
    float m = logits[0];
    for (int c=1;c<NCz;c++) m = fmaxf(m, logits[c]);
    float ssum = 0.f; float e[NCz];
    for (int c=0;c<NCz;c++){ e[c] = expf(logits[c]-m); ssum += e[c]; }
    for (int c=0;c<NCz;c++) out[b*NCz + c] = e[c]/ssum;
  }
}

extern "C" void kernel_launch(void* const* d_in, const int* in_sizes, int n_in,
                              void* d_out, int out_size, void* d_ws, size_t ws_size,
                              hipStream_t stream){
  const float* input_ids  = (const float*)d_in[0];
  const float* in_norm_w  = (const float*)d_in[1];
  const float* in2m_w     = (const float*)d_in[2];
  const float* in2m_b     = (const float*)d_in[3];
  const float* norm_w     = (const float*)d_in[4];
  const float* in_proj_w  = (const float*)d_in[5];
  const float* conv_w     = (const float*)d_in[6];
  const float* conv_b     = (const float*)d_in[7];
  const float* x_proj_w   = (const float*)d_in[8];
  const float* dt_proj_w  = (const float*)d_in[9];
  const float* dt_proj_b  = (const float*)d_in[10];
  const float* A_log      = (const float*)d_in[11];
  const float* D_param    = (const float*)d_in[12];
  const float* out_proj_w = (const float*)d_in[13];
  const float* norm_f_w   = (const float*)d_in[14];
  const float* head_w     = (const float*)d_in[15];
  const float* head_b     = (const float*)d_in[16];

  float* ws  = (float*)d_ws;
  float* res = ws;                  // B*L*DM   = 524288
  float* hs  = res + 524288;        // B*L*DM (hs0)
  float* xin = hs  + 524288;        // B*L*DI
  float* zb  = xin + 1048576;       // B*L*DI
  float* yg  = zb  + 1048576;       // B*L*DI (scan3 out)
  float* dtb = yg  + 1048576;       // B*L*DI (also aliased as xn)
  float* Bmb = dtb + 1048576;       // B*L*DS
  float* Cmb = Bmb + 65536;         // B*L*DS
  float* Pb  = Cmb + 65536;         // NCH*B*DI*DS = 2097152
  float* Hb  = Pb  + 2097152;
  float* hst = Hb  + 2097152;
  float* xn  = dtb;                 // alias: xn dead before k_xprojc writes dtb
  float* hs1 = Pb;                  // alias: Pb dead after k_scan2; k_norm consumes
                                    // hs1 before next layer's k_scan1 rewrites Pb

  k_embed<<<Bz*Lz, DMz, 0, stream>>>(input_ids, in_norm_w, in2m_w, in2m_b, hs);
  for (int i=0;i<NLz;i++){
    k_norm<<<(Bz*Lz)/4, 256, 0, stream>>>(hs, hs1, res, norm_w + i*DMz, xn, i==0);
    k_gemm_in<<<dim3(128, 8), 256, 0, stream>>>(xn, in_proj_w + (size_t)i*2*DIz*DMz, xin, zb);
    k_xprojc<<<(Bz*Lz)/XT, 256, 0, stream>>>(xin, conv_w + i*DIz*DCz, conv_b + i*DIz,
                                             x_proj_w + (size_t)i*(DTRz+2*DSz)*DIz,
                                             dt_proj_w + (size_t)i*DIz*DTRz, dt_proj_b + i*DIz,
                                             dtb, Bmb, Cmb);
    k_scan1<<<Bz*NCH, 256, 0, stream>>>(xin, dtb, Bmb, conv_w + i*DIz*DCz, conv_b + i*DIz,
                                        A_log + i*DIz*DSz, Pb, Hb);
    k_scan2<<<(Bz*DIz*DSz)/256, 256, 0, stream>>>(Pb, Hb, hst);
    k_scan3<<<Bz*NCH, 256, 0, stream>>>(xin, dtb, Bmb, Cmb, zb,
                                        conv_w + i*DIz*DCz, conv_b + i*DIz,
                                        A_log + i*DIz*DSz, D_param + i*DIz, hst, yg);
    k_gemm_out<<<dim3(128, 2, 2), 256, 0, stream>>>(yg, out_proj_w + (size_t)i*DMz*DIz, hs, hs1);
  }
  k_head<<<Bz, DMz, 0, stream>>>(hs, hs1, res, norm_f_w, head_w, head_b, (float*)d_out);
}

// Round 7
// 456.988 us; speedup vs baseline: 4.3221x; 1.1012x over previous
//
#include <hip/hip_runtime.h>
#include <hip/hip_bf16.h>

// Problem constants
#define Bz   2
#define Lz   2048
#define CINz 20
#define DMz  128
#define DIz  256
#define DSz  16
#define DTRz 8
#define DCz  4
#define NLz  6
#define NCz  6
#define EPSz 1e-5f
#define CHUNK 8
#define NCH   256   // Lz / CHUNK
#define XT    8     // tokens per xprojc block

__device__ __forceinline__ float siluf(float x){ return x / (1.0f + expf(-x)); }
__device__ __forceinline__ float softplusf(float x){ return (x > 20.f) ? x : log1pf(expf(x)); }

// ---- K1: embed = rmsnorm(input_ids) @ in2m_w.T + b, silu -> hs (B,L,DM)
__global__ void k_embed(const float* __restrict__ ids, const float* __restrict__ nw,
                        const float* __restrict__ w, const float* __restrict__ b,
                        float* __restrict__ hs){
  int tok = blockIdx.x;          // B*L
  int t = threadIdx.x;           // DM=128
  __shared__ float xs[CINz];
  if (t < CINz) xs[t] = ids[tok*CINz + t];
  __syncthreads();
  float ss = 0.f;
  #pragma unroll
  for (int k=0;k<CINz;k++){ float v = xs[k]; ss += v*v; }
  float rs = rsqrtf(ss/(float)CINz + EPSz);
  float acc = b[t];
  const float* wr = w + (size_t)t*CINz;
  #pragma unroll
  for (int k=0;k<CINz;k++) acc += xs[k]*rs*nw[k]*wr[k];
  hs[tok*DMz + t] = siluf(acc);
}

// ---- K2a: res update + rmsnorm*norm_w -> xn (4 tokens/block). hs = hs0+hs1
__global__ void k_norm(const float* __restrict__ hs0, const float* __restrict__ hs1,
                       float* __restrict__ res, const float* __restrict__ norm_w,
                       float* __restrict__ xn, int first){
  int tok = blockIdx.x*4 + (threadIdx.x >> 6);
  int lane = threadIdx.x & 63;
  size_t off = (size_t)tok*DMz + lane*2;
  float2 h = *(const float2*)(hs0 + off);
  float2 r2;
  if (first){ r2 = h; }
  else {
    float2 h1 = *(const float2*)(hs1 + off);
    float2 rr = *(const float2*)(res + off);
    r2 = make_float2(h.x+h1.x+rr.x, h.y+h1.y+rr.y);
  }
  *(float2*)(res + off) = r2;
  float ss = r2.x*r2.x + r2.y*r2.y;
  #pragma unroll
  for (int off2=32; off2; off2>>=1) ss += __shfl_xor(ss, off2);
  float rs = rsqrtf(ss*(1.0f/DMz) + EPSz);
  float2 nw = *(const float2*)(norm_w + lane*2);
  *(float2*)(xn + off) = make_float2(r2.x*rs*nw.x, r2.y*rs*nw.y);
}

// ---- K2b: xz = xn @ in_w.T   M=4096 N=512 K=128; tile 32x64, grid (128,8)
__global__ void k_gemm_in(const float* __restrict__ xn, const float* __restrict__ in_w,
                          float* __restrict__ xin, float* __restrict__ zb){
  __shared__ __align__(16) float As[32][132];
  __shared__ __align__(16) float Ws[64][132];
  int tb = blockIdx.x, nb = blockIdx.y, tid = threadIdx.x;
  #pragma unroll
  for (int i=tid; i<32*DMz/4; i+=256){
    int row = i >> 5, c4 = i & 31;
    *(float4*)&As[row][c4*4] = *(const float4*)(xn + (size_t)(tb*32+row)*DMz + c4*4);
  }
  #pragma unroll
  for (int i=tid; i<64*DMz/4; i+=256){
    int row = i >> 5, c4 = i & 31;
    *(float4*)&Ws[row][c4*4] = *(const float4*)(in_w + (size_t)(nb*64+row)*DMz + c4*4);
  }
  __syncthreads();
  int tp = tid >> 4;      // token pair 0..15
  int cl = tid & 15;      // col lane; cols cl+16j
  float acc[2][4] = {};
  for (int k=0;k<DMz;k+=4){
    float4 a0 = *(const float4*)&As[tp*2+0][k];
    float4 a1 = *(const float4*)&As[tp*2+1][k];
    #pragma unroll
    for (int j=0;j<4;j++){
      float4 w = *(const float4*)&Ws[cl+16*j][k];
      acc[0][j] = fmaf(a0.x,w.x, fmaf(a0.y,w.y, fmaf(a0.z,w.z, fmaf(a0.w,w.w, acc[0][j]))));
      acc[1][j] = fmaf(a1.x,w.x, fmaf(a1.y,w.y, fmaf(a1.z,w.z, fmaf(a1.w,w.w, acc[1][j]))));
    }
  }
  #pragma unroll
  for (int i=0;i<2;i++){
    int gt = tb*32 + tp*2 + i;
    #pragma unroll
    for (int j=0;j<4;j++){
      int c = nb*64 + cl + 16*j;
      if (c < DIz) xin[(size_t)gt*DIz + c] = acc[i][j];
      else         zb [(size_t)gt*DIz + (c-DIz)] = acc[i][j];
    }
  }
}

// ---- K4: fused conv+silu + xproj + dt for an 8-token tile (512 blocks)
__global__ void k_xprojc(const float* __restrict__ xin, const float* __restrict__ cw,
                         const float* __restrict__ cb, const float* __restrict__ xp_w,
                         const float* __restrict__ dt_w, const float* __restrict__ dt_b,
                         float* __restrict__ dt, float* __restrict__ Bm, float* __restrict__ Cm){
  __shared__ __align__(16) float xs[XT+3][DIz];   // 11.3 KB
  __shared__ __align__(16) float us[XT][DIz];     // 8 KB
  __shared__ float xd[XT][40];
  int tb = blockIdx.x;           // 0..511
  int b  = tb >> 8;              // / (Lz/XT)
  int l0 = (tb & 255) * XT;
  int tid = threadIdx.x;
  // stage xin rows l0-3 .. l0+XT-1 (zero-pad l<0): (XT+3)*64 float4
  for (int i = tid; i < (XT+3)*(DIz/4); i += 256){
    int r = i >> 6, c4 = (i & 63)*4;
    int l = l0 - 3 + r;
    float4 v = make_float4(0,0,0,0);
    if (l >= 0) v = *(const float4*)(xin + ((size_t)(b*Lz + l))*DIz + c4);
    *(float4*)&xs[r][c4] = v;
  }
  __syncthreads();
  // conv+silu into us: thread d = tid
  {
    int d = tid;
    float c0 = cw[d*DCz+0], c1 = cw[d*DCz+1], c2 = cw[d*DCz+2], c3 = cw[d*DCz+3];
    float bb = cb[d];
    #pragma unroll
    for (int tt=0; tt<XT; tt++){
      float acc = bb + xs[tt][d]*c0 + xs[tt+1][d]*c1 + xs[tt+2][d]*c2 + xs[tt+3][d]*c3;
      us[tt][d] = acc / (1.f + __expf(-acc));
    }
  }
  __syncthreads();
  // xdbl: 160 threads: c = t>>2 (0..39), kg = t&3; dot over 64 k-elems each
  if (tid < 160){
    int c = tid >> 2, kg = tid & 3;
    const float* wrow = xp_w + (size_t)c*DIz;
    float4 wreg[16];
    #pragma unroll
    for (int m=0;m<16;m++) wreg[m] = *(const float4*)(wrow + kg*4 + m*16);
    #pragma unroll
    for (int tt=0; tt<XT; tt++){
      float a = 0.f;
      #pragma unroll
      for (int m=0;m<16;m++){
        float4 uv = *(const float4*)&us[tt][kg*4 + m*16];
        float4 wv = wreg[m];
        a += uv.x*wv.x + uv.y*wv.y + uv.z*wv.z + uv.w*wv.w;
      }
      a += __shfl_down(a, 2);
      a += __shfl_down(a, 1);
      if (kg == 0) xd[tt][c] = a;
    }
  }
  __syncthreads();
  // dt: thread d for all XT tokens; Bm/Cm split writes (tid<128)
  {
    int d = tid;
    float w0[DTRz];
    #pragma unroll
    for (int k=0;k<DTRz;k++) w0[k] = dt_w[(size_t)d*DTRz + k];
    float bias = dt_b[d];
    #pragma unroll
    for (int tt=0; tt<XT; tt++){
      float s = bias;
      #pragma unroll
      for (int k=0;k<DTRz;k++) s += xd[tt][k]*w0[k];
      dt[((size_t)(b*Lz + l0 + tt))*DIz + d] = softplusf(s);
    }
    if (tid < XT*DSz){
      int tt = tid >> 4, s2 = tid & 15;
      Bm[((size_t)(b*Lz + l0 + tt))*DSz + s2] = xd[tt][DTRz + s2];
      Cm[((size_t)(b*Lz + l0 + tt))*DSz + s2] = xd[tt][DTRz + DSz + s2];
    }
  }
}

// ---- K5: chunk-local scan, thread-per-d, 16 states in regs; conv recomputed inline
__global__ void k_scan1(const float* __restrict__ xin, const float* __restrict__ dt,
                        const float* __restrict__ Bm,
                        const float* __restrict__ cw, const float* __restrict__ cb,
                        const float* __restrict__ A_log,
                        float* __restrict__ P, float* __restrict__ H){
  int bid = blockIdx.x;           // Bz*NCH = 512
  int b = bid >> 8;
  int ch = bid & (NCH-1);
  int d = threadIdx.x;
  __shared__ float B_l[CHUNK][DSz];
  if (threadIdx.x < CHUNK*DSz){
    int tt = threadIdx.x >> 4, s = threadIdx.x & 15;
    B_l[tt][s] = Bm[((size_t)(b*Lz + ch*CHUNK + tt))*DSz + s];
  }
  float Av[DSz];
  #pragma unroll
  for (int q=0;q<4;q++){
    float4 al = *(const float4*)(A_log + d*DSz + q*4);
    Av[q*4+0] = -__expf(al.x); Av[q*4+1] = -__expf(al.y);
    Av[q*4+2] = -__expf(al.z); Av[q*4+3] = -__expf(al.w);
  }
  float c0=cw[d*DCz],c1=cw[d*DCz+1],c2=cw[d*DCz+2],c3=cw[d*DCz+3], bb=cb[d];
  int l0 = ch*CHUNK;
  size_t base = (size_t)(b*Lz + l0)*DIz + d;
  float w0=0.f, w1=0.f, w2=0.f;
  if (l0 >= 3){ w0 = xin[base - 3*DIz]; w1 = xin[base - 2*DIz]; w2 = xin[base - DIz]; }
  __syncthreads();
  float h[DSz], Pp[DSz];
  #pragma unroll
  for (int s=0;s<DSz;s++){ h[s]=0.f; Pp[s]=1.f; }
  #pragma unroll
  for (int tt=0; tt<CHUNK; tt++){
    float w3  = xin[base + (size_t)tt*DIz];
    float dtv = dt[base + (size_t)tt*DIz];
    float uacc = bb + w0*c0 + w1*c1 + w2*c2 + w3*c3;
    float u = uacc / (1.f + __expf(-uacc));
    w0=w1; w1=w2; w2=w3;
    float x = dtv*u;
    #pragma unroll
    for (int s=0;s<DSz;s++){
      float a = __expf(dtv*Av[s]);
      h[s] = a*h[s] + x*B_l[tt][s];
      Pp[s] *= a;
    }
  }
  size_t o = ((size_t)(ch*Bz + b)*DIz + d)*DSz;
  #pragma unroll
  for (int q=0;q<4;q++){
    *(float4*)(P + o + q*4) = make_float4(Pp[q*4],Pp[q*4+1],Pp[q*4+2],Pp[q*4+3]);
    *(float4*)(H + o + q*4) = make_float4(h[q*4],h[q*4+1],h[q*4+2],h[q*4+3]);
  }
}

// ---- K6: sequential combine across NCH chunks -> hstart per chunk
__global__ void k_scan2(const float* __restrict__ P, const float* __restrict__ H,
                        float* __restrict__ hstart){
  int idx = blockIdx.x*256 + threadIdx.x;   // B*DI*DS = 8192
  float h = 0.f;
  for (int c0=0; c0<NCH; c0+=32){
    float p[32], q[32];
    #pragma unroll
    for (int j=0;j<32;j++){
      int o = (c0+j)*(Bz*DIz*DSz) + idx;
      p[j] = P[o]; q[j] = H[o];
    }
    #pragma unroll
    for (int j=0;j<32;j++){
      int o = (c0+j)*(Bz*DIz*DSz) + idx;
      hstart[o] = h;
      h = p[j]*h + q[j];
    }
  }
}

// ---- K7: replay chunk with correct h0, produce y, gate -> yg
__global__ void k_scan3(const float* __restrict__ xin, const float* __restrict__ dt,
                        const float* __restrict__ Bm, const float* __restrict__ Cm,
                        const float* __restrict__ z,
                        const float* __restrict__ cw, const float* __restrict__ cb,
                        const float* __restrict__ A_log, const float* __restrict__ Dp,
                        const float* __restrict__ hstart, float* __restrict__ yg){
  int bid = blockIdx.x;
  int b = bid >> 8;
  int ch = bid & (NCH-1);
  int d = threadIdx.x;
  __shared__ float B_l[CHUNK][DSz], C_l[CHUNK][DSz];
  if (threadIdx.x < CHUNK*DSz){
    int tt = threadIdx.x >> 4, s = threadIdx.x & 15;
    B_l[tt][s] = Bm[((size_t)(b*Lz + ch*CHUNK + tt))*DSz + s];
  } else if (threadIdx.x < 2*CHUNK*DSz){
    int t2 = threadIdx.x - CHUNK*DSz;
    int tt = t2 >> 4, s = t2 & 15;
    C_l[tt][s] = Cm[((size_t)(b*Lz + ch*CHUNK + tt))*DSz + s];
  }
  float Av[DSz];
  #pragma unroll
  for (int q=0;q<4;q++){
    float4 al = *(const float4*)(A_log + d*DSz + q*4);
    Av[q*4+0] = -__expf(al.x); Av[q*4+1] = -__expf(al.y);
    Av[q*4+2] = -__expf(al.z); Av[q*4+3] = -__expf(al.w);
  }
  float c0=cw[d*DCz],c1=cw[d*DCz+1],c2=cw[d*DCz+2],c3=cw[d*DCz+3], bb=cb[d];
  float Dv = Dp[d];
  int l0 = ch*CHUNK;
  size_t base = (size_t)(b*Lz + l0)*DIz + d;
  float w0=0.f, w1=0.f, w2=0.f;
  if (l0 >= 3){ w0 = xin[base - 3*DIz]; w1 = xin[base - 2*DIz]; w2 = xin[base - DIz]; }
  float h[DSz];
  {
    size_t o = ((size_t)(ch*Bz + b)*DIz + d)*DSz;
    #pragma unroll
    for (int q=0;q<4;q++){
      float4 hv = *(const float4*)(hstart + o + q*4);
      h[q*4+0]=hv.x; h[q*4+1]=hv.y; h[q*4+2]=hv.z; h[q*4+3]=hv.w;
    }
  }
  __syncthreads();
  #pragma unroll
  for (int tt=0; tt<CHUNK; tt++){
    float w3  = xin[base + (size_t)tt*DIz];
    float dtv = dt[base + (size_t)tt*DIz];
    float zv  = z[base + (size_t)tt*DIz];
    float uacc = bb + w0*c0 + w1*c1 + w2*c2 + w3*c3;
    float u = uacc / (1.f + __expf(-uacc));
    w0=w1; w1=w2; w2=w3;
    float x = dtv*u;
    float y = 0.f;
    #pragma unroll
    for (int s=0;s<DSz;s++){
      float a = __expf(dtv*Av[s]);
      h[s] = a*h[s] + x*B_l[tt][s];
      y += h[s]*C_l[tt][s];
    }
    float yv = y + u*Dv;
    yg[base + (size_t)tt*DIz] = yv * (zv / (1.f + __expf(-zv)));
  }
}

// ---- K8: hs_part[kz] = yg @ out_w.T  M=4096 N=128 K=256; grid (128,2,2)
__global__ void k_gemm_out(const float* __restrict__ yg, const float* __restrict__ out_w,
                           float* __restrict__ hs0, float* __restrict__ hs1){
  __shared__ __align__(16) float As[32][132];
  __shared__ __align__(16) float Ws[64][132];
  int tb = blockIdx.x, nb = blockIdx.y, kz = blockIdx.z, tid = threadIdx.x;
  int k0 = kz*128;
  #pragma unroll
  for (int i=tid; i<32*128/4; i+=256){
    int row = i >> 5, c4 = i & 31;
    *(float4*)&As[row][c4*4] = *(const float4*)(yg + (size_t)(tb*32+row)*DIz + k0 + c4*4);
  }
  #pragma unroll
  for (int i=tid; i<64*128/4; i+=256){
    int row = i >> 5, c4 = i & 31;
    *(float4*)&Ws[row][c4*4] = *(const float4*)(out_w + (size_t)(nb*64+row)*DIz + k0 + c4*4);
  }
  __syncthreads();
  int tp = tid >> 4;
  int cl = tid & 15;
  float acc[2][4] = {};
  for (int k=0;k<128;k+=4){
    float4 a0 = *(const float4*)&As[tp*2+0][k];
    float4 a1 = *(const float4*)&As[tp*2+1][k];
    #pragma unroll
    for (int j=0;j<4;j++){
      float4 w = *(const float4*)&Ws[cl+16*j][k];
      acc[0][j] = fmaf(a0.x,w.x, fmaf(a0.y,w.y, fmaf(a0.z,w.z, fmaf(a0.w,w.w, acc[0][j]))));
      acc[1][j] = fmaf(a1.x,w.x, fmaf(a1.y,w.y, fmaf(a1.z,w.z, fmaf(a1.w,w.w, acc[1][j]))));
    }
  }
  float* dst = kz ? hs1 : hs0;
  #pragma unroll
  for (int i=0;i<2;i++){
    int gt = tb*32 + tp*2 + i;
    #pragma unroll
    for (int j=0;j<4;j++){
      dst[(size_t)gt*DMz + nb*64 + cl + 16*j] = acc[i][j];
    }
  }
}

// ---- K9: final rmsnorm(hs0+hs1+res) @ head_w.T + head_b, softmax -> out
__global__ void k_head(const float* __restrict__ hs0, const float* __restrict__ hs1,
                       const float* __restrict__ res,
                       const float* __restrict__ nfw, const float* __restrict__ hw,
                       const float* __restrict__ hb, float* __restrict__ out){
  int b = blockIdx.x; int t = threadIdx.x;   // 128
  __shared__ float xs[DMz];
  __shared__ float logits[NCz];
  int tok = b*Lz + (Lz-1);
  xs[t] = hs0[tok*DMz + t] + hs1[tok*DMz + t] + res[tok*DMz + t];
  __syncthreads();
  float ss = 0.f;
  #pragma unroll
  for (int k=0;k<DMz;k++){ float v = xs[k]; ss += v*v; }
  float rs = rsqrtf(ss/(float)DMz + EPSz);
  if (t < NCz){
    float a = hb[t];
    const float* wr = hw + (size_t)t*DMz;
    for (int k=0;k<DMz;k++) a += xs[k]*rs*nfw[k]*wr[k];
    logits[t] = a;
  }
  __syncthreads();
  if (t == 0){
    float m = logits[0];
    for (int c=1;c<NCz;c++) m = fmaxf(m, logits[c]);
    float ssum = 0.f; float e[NCz];
    for (int c=0;c<NCz;c++){ e[c] = expf(logits[c]-m); ssum += e[c]; }
    for (int c=0;c<NCz;c++) out[b*NCz + c] = e[c]/ssum;
  }
}

extern "C" void kernel_launch(void* const* d_in, const int* in_sizes, int n_in,
                              void* d_out, int out_size, void* d_ws, size_t ws_size,
                              hipStream_t stream){
  const float* input_ids  = (const float*)d_in[0];
  const float* in_norm_w  = (const float*)d_in[1];
  const float* in2m_w     = (const float*)d_in[2];
  const float* in2m_b     = (const float*)d_in[3];
  const float* norm_w     = (const float*)d_in[4];
  const float* in_proj_w  = (const float*)d_in[5];
  const float* conv_w     = (const float*)d_in[6];
  const float* conv_b     = (const float*)d_in[7];
  const float* x_proj_w   = (const float*)d_in[8];
  const float* dt_proj_w  = (const float*)d_in[9];
  const float* dt_proj_b  = (const float*)d_in[10];
  const float* A_log      = (const float*)d_in[11];
  const float* D_param    = (const float*)d_in[12];
  const float* out_proj_w = (const float*)d_in[13];
  const float* norm_f_w   = (const float*)d_in[14];
  const float* head_w     = (const float*)d_in[15];
  const float* head_b     = (const float*)d_in[16];

  float* ws  = (float*)d_ws;
  float* res = ws;                  // B*L*DM   = 524288
  float* hs  = res + 524288;        // B*L*DM (hs0)
  float* xin = hs  + 524288;        // B*L*DI
  float* zb  = xin + 1048576;       // B*L*DI
  float* yg  = zb  + 1048576;       // B*L*DI (scan3 out)
  float* dtb = yg  + 1048576;       // B*L*DI (also aliased as xn)
  float* Bmb = dtb + 1048576;       // B*L*DS
  float* Cmb = Bmb + 65536;         // B*L*DS
  float* Pb  = Cmb + 65536;         // NCH*B*DI*DS = 2097152
  float* Hb  = Pb  + 2097152;
  float* hst = Hb  + 2097152;
  float* xn  = dtb;                 // alias: xn dead before k_xprojc writes dtb
  float* hs1 = Pb;                  // alias: Pb dead after k_scan2; k_norm consumes
                                    // hs1 before next layer's k_scan1 rewrites Pb

  k_embed<<<Bz*Lz, DMz, 0, stream>>>(input_ids, in_norm_w, in2m_w, in2m_b, hs);
  for (int i=0;i<NLz;i++){
    k_norm<<<(Bz*Lz)/4, 256, 0, stream>>>(hs, hs1, res, norm_w + i*DMz, xn, i==0);
    k_gemm_in<<<dim3(128, 8), 256, 0, stream>>>(xn, in_proj_w + (size_t)i*2*DIz*DMz, xin, zb);
    k_xprojc<<<(Bz*Lz)/XT, 256, 0, stream>>>(xin, conv_w + i*DIz*DCz, conv_b + i*DIz,
                                             x_proj_w + (size_t)i*(DTRz+2*DSz)*DIz,
                                             dt_proj_w + (size_t)i*DIz*DTRz, dt_proj_b + i*DIz,
                                             dtb, Bmb, Cmb);
    k_scan1<<<Bz*NCH, 256, 0, stream>>>(xin, dtb, Bmb, conv_w + i*DIz*DCz, conv_b + i*DIz,
                                        A_log + i*DIz*DSz, Pb, Hb);
    k_scan2<<<(Bz*DIz*DSz)/256, 256, 0, stream>>>(Pb, Hb, hst);
    k_scan3<<<Bz*NCH, 256, 0, stream>>>(xin, dtb, Bmb, Cmb, zb,
                                        conv_w + i*DIz*DCz, conv_b + i*DIz,
                                        A_log + i*DIz*DSz, D_param + i*DIz, hst, yg);
    k_gemm_out<<<dim3(128, 2, 2), 256, 0, stream>>>(yg, out_proj_w + (size_t)i*DMz*DIz, hs, hs1);
  }
  k_head<<<Bz, DMz, 0, stream>>>(hs, hs1, res, norm_f_w, head_w, head_b, (float*)d_out);
}